// Round 9
// baseline (650.265 us; speedup 1.0000x reference)
//
#include <hip/hip_runtime.h>
#include <hip/hip_fp16.h>
#include <cstddef>
#include <type_traits>

#define N_NODES 50000
#define E_EDGES 1000000
#define NBUCK 196          // ceil(50000/256) node-buckets (node>>8)
#define ACHUNK 3907        // ceil(E/256) edges per binning block
#define MTILES 3125        // 50000 / 16
#define HB 96              // hist blocks per index array
#define HCHUNK 10417       // ceil(E/96)
#define GB1 384            // layer-1 gemm blocks per relation
#define GB2 256            // layer-2 gemm blocks per relation
#define SLNB 1024          // spmm blocks per slice (grid = 8*SLNB)
// IN = 128, HID = 128, OUT = 64

typedef _Float16 f16x8 __attribute__((ext_vector_type(8)));
typedef float f32x4 __attribute__((ext_vector_type(4)));

// ---------------- dispatch 1: weight cvt/transpose  ||  hist partials --------
__global__ __launch_bounds__(256) void fused0(
        const float* __restrict__ w0, const float* __restrict__ w1,
        const float* __restrict__ w2, const float* __restrict__ w3,
        const float* __restrict__ w4, const float* __restrict__ w5,
        __half* __restrict__ Wt,
        const int* __restrict__ rs, const int* __restrict__ rd,
        const int* __restrict__ bs, const int* __restrict__ bd,
        const int* __restrict__ fs, const int* __restrict__ fd,
        int* __restrict__ bphist) {
    int bx = blockIdx.x;
    if (bx < 6 * HB) {
        __shared__ int l[NBUCK];
        int arr = bx / HB, blk = bx % HB;
        const int* idx = arr == 0 ? rs : arr == 1 ? rd : arr == 2 ? bs
                       : arr == 3 ? bd : arr == 4 ? fs : fd;
        for (int b = threadIdx.x; b < NBUCK; b += 256) l[b] = 0;
        __syncthreads();
        int e0 = blk * HCHUNK;
        int e1 = e0 + HCHUNK; if (e1 > E_EDGES) e1 = E_EDGES;
        for (int i = e0 + threadIdx.x; i < e1; i += 256)
            atomicAdd(&l[((unsigned)idx[i]) >> 8], 1);
        __syncthreads();
        int* dst = bphist + (size_t)(arr * HB + blk) * NBUCK;
        for (int b = threadIdx.x; b < NBUCK; b += 256) dst[b] = l[b];
        return;
    }
    bx -= 6 * HB;
    int m = bx / 16, part = bx % 16;
    const float* W = m == 0 ? w0 : m == 1 ? w1 : m == 2 ? w2 : m == 3 ? w3 : m == 4 ? w4 : w5;
    __half* Tt = Wt + (m < 3 ? m * 16384 : 49152 + (m - 3) * 8192);
    int ncol = m < 3 ? 128 : 64;
    int tot = 128 * ncol;
    for (int i = part * 256 + threadIdx.x; i < tot; i += 16 * 256) {
        int n = i >> 7, k = i & 127;          // Wt[n][k] = W[k][n]
        Tt[i] = __float2half(W[k * ncol + n]);
    }
}

// ---------------- dispatch 2: parallel bucket scan -> gbase, gcur ------------
__global__ void bucket_scan_par(const int* __restrict__ bphist, int* __restrict__ gbase,
                                int* __restrict__ gcur) {
    int arr = blockIdx.x;   // 0..5
    int t = threadIdx.x;    // 256
    int c = 0;
    if (t < NBUCK) {
        const int* p = bphist + (size_t)arr * HB * NBUCK + t;
#pragma unroll 8
        for (int blk = 0; blk < HB; blk++) c += p[(size_t)blk * NBUCK];
    }
    int lane = t & 63, wid = t >> 6;
    __shared__ int wsum[4];
    int v = c;
#pragma unroll
    for (int o = 1; o < 64; o <<= 1) { int u = __shfl_up(v, o); if (lane >= o) v += u; }
    if (lane == 63) wsum[wid] = v;
    __syncthreads();
    int base = 0;
    for (int ww = 0; ww < wid; ww++) base += wsum[ww];
    int excl = base + v - c;
    if (t < NBUCK) {
        gbase[arr * (NBUCK + 1) + t] = excl;
        gcur[arr * NBUCK + t] = excl;
    }
    if (t == 255) gbase[arr * (NBUCK + 1) + NBUCK] = base + v;   // == E
}

// ---------------- dispatch 3: binP (y<3) || binS (y>=3) ----------------------
__global__ __launch_bounds__(256) void fused_bin(
        const int* __restrict__ rs, const int* __restrict__ rd,
        const int* __restrict__ bs, const int* __restrict__ bd,
        const int* __restrict__ fs, const int* __restrict__ fd,
        int* __restrict__ gcur, unsigned* __restrict__ pairs,
        unsigned char* __restrict__ sbytes) {
    int y = blockIdx.y;
    __shared__ int lcnt[NBUCK];
    __shared__ int lbase[NBUCK];
    int e0 = blockIdx.x * ACHUNK;
    int e1 = e0 + ACHUNK; if (e1 > E_EDGES) e1 = E_EDGES;
    for (int b = threadIdx.x; b < NBUCK; b += 256) lcnt[b] = 0;
    __syncthreads();
    if (y < 3) {
        int rel = y, arr = 2 * rel + 1;
        const int* src = rel == 0 ? rs : rel == 1 ? bs : fs;
        const int* dst = rel == 0 ? rd : rel == 1 ? bd : fd;
        for (int i = e0 + threadIdx.x; i < e1; i += 256)
            atomicAdd(&lcnt[((unsigned)dst[i]) >> 8], 1);
        __syncthreads();
        for (int b = threadIdx.x; b < NBUCK; b += 256) {
            lbase[b] = lcnt[b] ? atomicAdd(&gcur[arr * NBUCK + b], lcnt[b]) : 0;
            lcnt[b] = 0;
        }
        __syncthreads();
        unsigned* pp = pairs + (size_t)rel * E_EDGES;
        for (int i = e0 + threadIdx.x; i < e1; i += 256) {
            int d = dst[i];
            int b = ((unsigned)d) >> 8;
            int p = lbase[b] + atomicAdd(&lcnt[b], 1);
            pp[p] = ((unsigned)(d & 255) << 16) | (unsigned)src[i];
        }
    } else {
        int rel = y - 3, arr = 2 * rel;
        const int* src = rel == 0 ? rs : rel == 1 ? bs : fs;
        for (int i = e0 + threadIdx.x; i < e1; i += 256)
            atomicAdd(&lcnt[((unsigned)src[i]) >> 8], 1);
        __syncthreads();
        for (int b = threadIdx.x; b < NBUCK; b += 256) {
            lbase[b] = lcnt[b] ? atomicAdd(&gcur[arr * NBUCK + b], lcnt[b]) : 0;
            lcnt[b] = 0;
        }
        __syncthreads();
        unsigned char* sb = sbytes + (size_t)rel * E_EDGES;
        for (int i = e0 + threadIdx.x; i < e1; i += 256) {
            int s = src[i];
            int b = ((unsigned)s) >> 8;
            int p = lbase[b] + atomicAdd(&lcnt[b], 1);
            sb[p] = (unsigned char)(s & 255);
        }
    }
}

// ---------------- dispatch 4: countS (y<3) || fillB2 (y>=3) ------------------
__global__ __launch_bounds__(256) void fused_finish(
        const unsigned* __restrict__ pairs, const unsigned char* __restrict__ sbytes,
        const int* __restrict__ gbase, int* __restrict__ row_ptr,
        float* __restrict__ scales, int* __restrict__ col) {
    int y = blockIdx.y, b = blockIdx.x, t = threadIdx.x;
    __shared__ int cnt[256];
    __shared__ int rowbase[256];
    __shared__ int wsum[4];
    if (y < 3) {
        int rel = y, arr = 2 * rel;
        int p0 = gbase[arr * (NBUCK + 1) + b];
        int p1 = gbase[arr * (NBUCK + 1) + b + 1];
        const unsigned char* sb = sbytes + (size_t)rel * E_EDGES;
        cnt[t] = 0;
        __syncthreads();
        for (int i = p0 + t; i < p1; i += 256)
            atomicAdd(&cnt[sb[i]], 1);
        __syncthreads();
        int node = b * 256 + t;
        if (node < N_NODES) {
            int c = cnt[t]; if (c < 1) c = 1;
            scales[(size_t)arr * N_NODES + node] = 1.0f / sqrtf((float)c);
        }
    } else {
        int rel = y - 3, arr = 2 * rel + 1;
        int gb = gbase[arr * (NBUCK + 1) + b];
        int ge = gbase[arr * (NBUCK + 1) + b + 1];
        const unsigned* pp = pairs + (size_t)rel * E_EDGES;
        cnt[t] = 0;
        __syncthreads();
        for (int i = gb + t; i < ge; i += 256)
            atomicAdd(&cnt[pp[i] >> 16], 1);
        __syncthreads();
        int lane = t & 63, wid = t >> 6;
        int c0 = cnt[t];
        int v = c0;
#pragma unroll
        for (int o = 1; o < 64; o <<= 1) { int u = __shfl_up(v, o); if (lane >= o) v += u; }
        if (lane == 63) wsum[wid] = v;
        __syncthreads();
        int base = gb;
        for (int w = 0; w < wid; w++) base += wsum[w];
        int excl = base + v - c0;
        rowbase[t] = excl;
        int node = b * 256 + t;
        if (node <= N_NODES)
            row_ptr[(size_t)rel * (N_NODES + 1) + node] = excl;
        if (node < N_NODES) {
            int c = c0; if (c < 1) c = 1;
            scales[(size_t)arr * N_NODES + node] = 1.0f / sqrtf((float)c);
        }
        cnt[t] = 0;   // reuse as per-row cursor
        __syncthreads();
        int* cl = col + (size_t)rel * E_EDGES;
        for (int i = gb + t; i < ge; i += 256) {
            unsigned p = pp[i];
            int dl = p >> 16;
            int slot = rowbase[dl] + atomicAdd(&cnt[dl], 1);
            cl[slot] = (int)(p & 0xFFFFu);
        }
    }
}

// --------------------------------------------- MFMA GEMM body: T = diag(s)*(X@W)
// Output written in SLICE-MAJOR layout for L2-resident sliced gathers:
//   NCOL=128: T[slice(16dims)][node][16]   slice = col>>4
//   NCOL=64 : T[slice(8dims) ][node][8]    slice = col>>3
// C/D layout: col = lane&15, row = (lane>>4)*4 + reg (HW-verified).
template <int NCOL, typename XT>
__device__ __forceinline__ void gemm_body(const XT* __restrict__ X,
                                          const float* __restrict__ sc,
                                          const __half* __restrict__ Wt,
                                          __half* __restrict__ T,
                                          int bxr, int nblocks) {
    constexpr int NHALF = NCOL / 64;        // 2 for 128, 1 for 64
    int gw = bxr * 4 + ((int)threadIdx.x >> 6);
    int lane = threadIdx.x & 63;
    int half_id = gw % NHALF;
    int mstream = gw / NHALF;
    int nstreams = nblocks * 4 / NHALF;
    int l15 = lane & 15, g = lane >> 4;

    f16x8 b[4][4];
    {
        const __half* wb = Wt + ((size_t)half_id * 64 + l15) * 128 + g * 8;
#pragma unroll
        for (int nt = 0; nt < 4; nt++)
#pragma unroll
            for (int kb = 0; kb < 4; kb++)
                b[nt][kb] = *(const f16x8*)(wb + nt * 16 * 128 + kb * 32);
    }

    for (int mt = mstream; mt < MTILES; mt += nstreams) {
        int m0 = mt * 16;
        f16x8 a[4];
        if constexpr (std::is_same<XT, float>::value) {
            const float* xr = X + (size_t)(m0 + l15) * 128 + g * 8;
#pragma unroll
            for (int kb = 0; kb < 4; kb++) {
                float4 u = *(const float4*)(xr + kb * 32);
                float4 v = *(const float4*)(xr + kb * 32 + 4);
                f16x8 t;
                t[0] = (_Float16)u.x; t[1] = (_Float16)u.y;
                t[2] = (_Float16)u.z; t[3] = (_Float16)u.w;
                t[4] = (_Float16)v.x; t[5] = (_Float16)v.y;
                t[6] = (_Float16)v.z; t[7] = (_Float16)v.w;
                a[kb] = t;
            }
        } else {
            const _Float16* xr = (const _Float16*)X + (size_t)(m0 + l15) * 128 + g * 8;
#pragma unroll
            for (int kb = 0; kb < 4; kb++)
                a[kb] = *(const f16x8*)(xr + kb * 32);
        }
        f32x4 acc[4];
#pragma unroll
        for (int nt = 0; nt < 4; nt++) acc[nt] = (f32x4){0.f, 0.f, 0.f, 0.f};
#pragma unroll
        for (int kb = 0; kb < 4; kb++)
#pragma unroll
            for (int nt = 0; nt < 4; nt++)
                acc[nt] = __builtin_amdgcn_mfma_f32_16x16x32_f16(a[kb], b[nt][kb], acc[nt], 0, 0, 0);
        int mrow = m0 + g * 4;
#pragma unroll
        for (int j = 0; j < 4; j++) {
            float sj = sc[mrow + j];
#pragma unroll
            for (int nt = 0; nt < 4; nt++) {
                int colv = half_id * 64 + nt * 16 + l15;
                __half val = __float2half(acc[nt][j] * sj);
                if constexpr (NCOL == 128) {
                    T[((size_t)(colv >> 4) * N_NODES + mrow + j) * 16 + (colv & 15)] = val;
                } else {
                    T[((size_t)(colv >> 3) * N_NODES + mrow + j) * 8 + (colv & 7)] = val;
                }
            }
        }
    }
}

// ---------------- dispatch 5: layer-1 GEMMs (3 relations) --------------------
__global__ __launch_bounds__(256) void gemm_l1(const float* __restrict__ fA,
                                               const float* __restrict__ fB,
                                               const float* __restrict__ scales,
                                               const __half* __restrict__ Wt,
                                               __half* __restrict__ T012) {
    int rel = blockIdx.x / GB1, bxr = blockIdx.x % GB1;
    const float* X = (rel == 1) ? fB : fA;
    const float* sc = scales + (rel == 0 ? 0 : rel == 1 ? 2 * N_NODES : 4 * N_NODES);
    const __half* W = Wt + rel * 16384;
    __half* T = T012 + (size_t)rel * N_NODES * 128;
    gemm_body<128, float>(X, sc, W, T, bxr, GB1);
}

// ---------------- dispatch 7: layer-2 GEMMs (3 relations) --------------------
__global__ __launch_bounds__(256) void gemm_l2(const __half* __restrict__ hA,
                                               const __half* __restrict__ hB,
                                               const float* __restrict__ scales,
                                               const __half* __restrict__ Wt,
                                               __half* __restrict__ Tp) {
    int rel = blockIdx.x / GB2, bxr = blockIdx.x % GB2;
    const __half* X = (rel == 1) ? hB : hA;
    const float* sc = scales + (rel == 0 ? 0 : rel == 1 ? 2 * N_NODES : 4 * N_NODES);
    const __half* W = Wt + 49152 + rel * 8192;
    __half* T = Tp + (size_t)rel * N_NODES * 64;
    gemm_body<64, __half>(X, sc, W, T, bxr, GB2);
}

// ---------------- dispatch 6: layer-1 sliced SpMM ----------------------------
// slice = blockIdx&7 -> one XCD owns one 16-dim slice (1.6MB x 3 rels, L2-resident).
// Wave: 8 lanes/edge (half2/lane), 4-edge groups x 2 streams; shfl group-reduce.
// items: t<25000 -> B-row pair (CSR0/T0); else A-row dual-stream (CSR1/T1 + CSR2/T2).
__global__ __launch_bounds__(256) void spmm_l1(
        const int* __restrict__ row_ptr, const int* __restrict__ col,
        const __half* __restrict__ T012, const float* __restrict__ scales,
        const float* __restrict__ b1r, const float* __restrict__ b1rb,
        const float* __restrict__ b1f,
        __half* __restrict__ hB, __half* __restrict__ hA) {
    int slice = blockIdx.x & 7;
    int wslice = (blockIdx.x >> 3) * 4 + ((int)threadIdx.x >> 6);
    const int nws = SLNB * 4;
    int lane = threadIdx.x & 63;
    int stream = lane >> 5;
    int gi = (lane >> 3) & 3;
    int li = lane & 7;
    unsigned lo4 = (unsigned)li << 2;
    const char* T0 = (const char*)T012 + (size_t)slice * 1600000;
    const char* T1 = (const char*)T012 + (size_t)(8 + slice) * 1600000;
    const char* T2 = (const char*)T012 + (size_t)(16 + slice) * 1600000;
    const int* rp1 = row_ptr + (N_NODES + 1);
    const int* rp2 = row_ptr + 2 * (N_NODES + 1);
    const int* cl1 = col + E_EDGES;
    const int* cl2 = col + 2 * (size_t)E_EDGES;
    int bi = slice * 16 + 2 * li;

    for (int t = wslice; t < 75000; t += nws) {
        float ax = 0.f, ay = 0.f;
        if (t < 25000) {
            int rowA = t * 2, rowB = rowA + 1;
            int begA = row_ptr[rowA], EA = row_ptr[rowA + 1], EB = row_ptr[rowB + 1];
            int myEnd = stream ? EB : EA;
            int e = (stream ? EA : begA) + gi;
            int rounds = max(EA - begA, EB - EA);
            rounds = (rounds + 3) >> 2;
#pragma unroll 2
            for (int r = 0; r < rounds; r++) {
                bool v = e < myEnd;
                int idx = min(e, myEnd - 1); idx = max(idx, 0);
                int c = col[idx];
                float2 val = __half22float2(*(const __half2*)(T0 + ((unsigned)c * 32u + lo4)));
                if (v) { ax += val.x; ay += val.y; }
                e += 4;
            }
            ax += __shfl_xor(ax, 8);  ay += __shfl_xor(ay, 8);
            ax += __shfl_xor(ax, 16); ay += __shfl_xor(ay, 16);
            if (gi == 0) {
                int row = stream ? rowB : rowA;
                float s = scales[N_NODES + row];
                float bx = b1r[bi], by = b1r[bi + 1];
                float ox = fmaxf(fmaf(ax, s, bx), 0.f);
                float oy = fmaxf(fmaf(ay, s, by), 0.f);
                *(__half2*)(hB + (size_t)row * 128 + bi) = __floats2half2_rn(ox, oy);
            }
        } else {
            int r0 = t - 25000;
            int e1b = rp1[r0], E1 = rp1[r0 + 1];
            int e2b = rp2[r0], E2 = rp2[r0 + 1];
            int myEnd = stream ? E2 : E1;
            int e = (stream ? e2b : e1b) + gi;
            const int* cp = stream ? cl2 : cl1;
            const char* Tb = stream ? T2 : T1;
            int rounds = max(E1 - e1b, E2 - e2b);
            rounds = (rounds + 3) >> 2;
#pragma unroll 2
            for (int r = 0; r < rounds; r++) {
                bool v = e < myEnd;
                int idx = min(e, myEnd - 1); idx = max(idx, 0);
                int c = cp[idx];
                float2 val = __half22float2(*(const __half2*)(Tb + ((unsigned)c * 32u + lo4)));
                if (v) { ax += val.x; ay += val.y; }
                e += 4;
            }
            ax += __shfl_xor(ax, 8);  ay += __shfl_xor(ay, 8);
            ax += __shfl_xor(ax, 16); ay += __shfl_xor(ay, 16);
            float s = scales[(stream ? 5 : 3) * N_NODES + r0];
            ax *= s; ay *= s;
            ax += __shfl_xor(ax, 32); ay += __shfl_xor(ay, 32);
            if (lane < 8) {
                float bx = b1rb[bi] + b1f[bi];
                float by = b1rb[bi + 1] + b1f[bi + 1];
                float ox = fmaxf(ax + bx, 0.f), oy = fmaxf(ay + by, 0.f);
                *(__half2*)(hA + (size_t)r0 * 128 + bi) = __floats2half2_rn(ox, oy);
            }
        }
    }
}

// ---------------- dispatch 8: layer-2 sliced SpMM (8-dim slices) -------------
__global__ __launch_bounds__(256) void spmm_l2(
        const int* __restrict__ row_ptr, const int* __restrict__ col,
        const __half* __restrict__ Tp, const float* __restrict__ scales,
        const float* __restrict__ b2r, const float* __restrict__ b2rb,
        const float* __restrict__ b2f,
        __half* __restrict__ oB, __half* __restrict__ oA) {
    int slice = blockIdx.x & 7;
    int wslice = (blockIdx.x >> 3) * 4 + ((int)threadIdx.x >> 6);
    const int nws = SLNB * 4;
    int lane = threadIdx.x & 63;
    int stream = lane >> 5;
    int gi = (lane >> 2) & 7;
    int li = lane & 3;
    unsigned lo4 = (unsigned)li << 2;
    const char* T0 = (const char*)Tp + (size_t)slice * 800000;
    const char* T1 = (const char*)Tp + (size_t)(8 + slice) * 800000;
    const char* T2 = (const char*)Tp + (size_t)(16 + slice) * 800000;
    const int* rp1 = row_ptr + (N_NODES + 1);
    const int* rp2 = row_ptr + 2 * (N_NODES + 1);
    const int* cl1 = col + E_EDGES;
    const int* cl2 = col + 2 * (size_t)E_EDGES;
    int bi = slice * 8 + 2 * li;

    for (int t = wslice; t < 75000; t += nws) {
        float ax = 0.f, ay = 0.f;
        if (t < 25000) {
            int rowA = t * 2, rowB = rowA + 1;
            int begA = row_ptr[rowA], EA = row_ptr[rowA + 1], EB = row_ptr[rowB + 1];
            int myEnd = stream ? EB : EA;
            int e = (stream ? EA : begA) + gi;
            int rounds = max(EA - begA, EB - EA);
            rounds = (rounds + 7) >> 3;
#pragma unroll 2
            for (int r = 0; r < rounds; r++) {
                bool v = e < myEnd;
                int idx = min(e, myEnd - 1); idx = max(idx, 0);
                int c = col[idx];
                float2 val = __half22float2(*(const __half2*)(T0 + ((unsigned)c * 16u + lo4)));
                if (v) { ax += val.x; ay += val.y; }
                e += 8;
            }
            ax += __shfl_xor(ax, 4);  ay += __shfl_xor(ay, 4);
            ax += __shfl_xor(ax, 8);  ay += __shfl_xor(ay, 8);
            ax += __shfl_xor(ax, 16); ay += __shfl_xor(ay, 16);
            if (gi == 0) {
                int row = stream ? rowB : rowA;
                float s = scales[N_NODES + row];
                float bx = b2r[bi], by = b2r[bi + 1];
                *(__half2*)(oB + (size_t)row * 64 + bi) =
                    __floats2half2_rn(fmaf(ax, s, bx), fmaf(ay, s, by));
            }
        } else {
            int r0 = t - 25000;
            int e1b = rp1[r0], E1 = rp1[r0 + 1];
            int e2b = rp2[r0], E2 = rp2[r0 + 1];
            int myEnd = stream ? E2 : E1;
            int e = (stream ? e2b : e1b) + gi;
            const int* cp = stream ? cl2 : cl1;
            const char* Tb = stream ? T2 : T1;
            int rounds = max(E1 - e1b, E2 - e2b);
            rounds = (rounds + 7) >> 3;
#pragma unroll 2
            for (int r = 0; r < rounds; r++) {
                bool v = e < myEnd;
                int idx = min(e, myEnd - 1); idx = max(idx, 0);
                int c = cp[idx];
                float2 val = __half22float2(*(const __half2*)(Tb + ((unsigned)c * 16u + lo4)));
                if (v) { ax += val.x; ay += val.y; }
                e += 8;
            }
            ax += __shfl_xor(ax, 4);  ay += __shfl_xor(ay, 4);
            ax += __shfl_xor(ax, 8);  ay += __shfl_xor(ay, 8);
            ax += __shfl_xor(ax, 16); ay += __shfl_xor(ay, 16);
            float s = scales[(stream ? 5 : 3) * N_NODES + r0];
            ax *= s; ay *= s;
            ax += __shfl_xor(ax, 32); ay += __shfl_xor(ay, 32);
            if (lane < 4) {
                float bx = b2rb[bi] + b2f[bi];
                float by = b2rb[bi + 1] + b2f[bi + 1];
                *(__half2*)(oA + (size_t)r0 * 64 + bi) = __floats2half2_rn(ax + bx, ay + by);
            }
        }
    }
}

// ---------------- dispatch 9: scoring (pos + neg fused) ----------------------
__global__ __launch_bounds__(256) void score2(const __half* __restrict__ oA,
                                              const __half* __restrict__ oB,
                                              const int* __restrict__ ps,
                                              const int* __restrict__ pd,
                                              const int* __restrict__ ns,
                                              const int* __restrict__ nd,
                                              float* __restrict__ out) {
    int g = (blockIdx.x * blockDim.x + threadIdx.x) >> 4;
    int l = threadIdx.x & 15;
    int ng = (gridDim.x * blockDim.x) >> 4;
    const char* A = (const char*)oA;
    const char* B = (const char*)oB;
    unsigned loff = (unsigned)l << 3;   // 4 halves per lane
#define SCORE_LOOP(SRC, DST, OUT)                                               \
    for (int e0 = g * 2; e0 < E_EDGES; e0 += ng * 2) {                          \
        int e1 = e0 + 1;                                                        \
        int s0 = SRC[e0], d0 = DST[e0], s1 = SRC[e1], d1 = DST[e1];             \
        union { uint2 u; __half2 h[2]; } a0, b0, a1, b1;                        \
        a0.u = *(const uint2*)(A + (((unsigned)s0 << 7) + loff));               \
        b0.u = *(const uint2*)(B + (((unsigned)d0 << 7) + loff));               \
        a1.u = *(const uint2*)(A + (((unsigned)s1 << 7) + loff));               \
        b1.u = *(const uint2*)(B + (((unsigned)d1 << 7) + loff));               \
        float2 fa, fb;                                                          \
        fa = __half22float2(a0.h[0]); fb = __half22float2(b0.h[0]);             \
        float p0 = fa.x * fb.x + fa.y * fb.y;                                   \
        fa = __half22float2(a0.h[1]); fb = __half22float2(b0.h[1]);             \
        p0 += fa.x * fb.x + fa.y * fb.y;                                        \
        fa = __half22float2(a1.h[0]); fb = __half22float2(b1.h[0]);             \
        float p1 = fa.x * fb.x + fa.y * fb.y;                                   \
        fa = __half22float2(a1.h[1]); fb = __half22float2(b1.h[1]);             \
        p1 += fa.x * fb.x + fa.y * fb.y;                                        \
        p0 += __shfl_xor(p0, 8); p1 += __shfl_xor(p1, 8);                       \
        p0 += __shfl_xor(p0, 4); p1 += __shfl_xor(p1, 4);                       \
        p0 += __shfl_xor(p0, 2); p1 += __shfl_xor(p1, 2);                       \
        p0 += __shfl_xor(p0, 1); p1 += __shfl_xor(p1, 1);                       \
        if (l == 0) { OUT[e0] = p0; OUT[e1] = p1; }                             \
    }
    SCORE_LOOP(ps, pd, out)
    float* outn = out + E_EDGES;
    SCORE_LOOP(ns, nd, outn)
#undef SCORE_LOOP
}

// ---------------------------------------------------------------------------
extern "C" void kernel_launch(void* const* d_in, const int* in_sizes, int n_in,
                              void* d_out, int out_size, void* d_ws, size_t ws_size,
                              hipStream_t stream) {
    const float* feat_A     = (const float*)d_in[0];
    const float* feat_B     = (const float*)d_in[1];
    const int* rates_src    = (const int*)d_in[2];
    const int* rates_dst    = (const int*)d_in[3];
    const int* ratedby_src  = (const int*)d_in[4];
    const int* ratedby_dst  = (const int*)d_in[5];
    const int* follows_src  = (const int*)d_in[6];
    const int* follows_dst  = (const int*)d_in[7];
    const int* neg_src      = (const int*)d_in[8];
    const int* neg_dst      = (const int*)d_in[9];
    const float* W1_rates   = (const float*)d_in[10];
    const float* b1_rates   = (const float*)d_in[11];
    const float* W1_ratedby = (const float*)d_in[12];
    const float* b1_ratedby = (const float*)d_in[13];
    const float* W1_follows = (const float*)d_in[14];
    const float* b1_follows = (const float*)d_in[15];
    const float* W2_rates   = (const float*)d_in[16];
    const float* b2_rates   = (const float*)d_in[17];
    const float* W2_ratedby = (const float*)d_in[18];
    const float* b2_ratedby = (const float*)d_in[19];
    const float* W2_follows = (const float*)d_in[20];
    const float* b2_follows = (const float*)d_in[21];

    const int N = N_NODES, E = E_EDGES;

    char* ws = (char*)d_ws;
    size_t off = 0;
    auto alloc = [&](size_t bytes) -> void* {
        void* p = ws + off;
        off += (bytes + 255) & ~(size_t)255;
        return p;
    };
    float* scales = (float*)alloc((size_t)6 * N * 4);
    int* row_ptr  = (int*)alloc((size_t)3 * (N + 1) * 4);
    int* bphist   = (int*)alloc((size_t)6 * HB * NBUCK * 4);
    int* gbase    = (int*)alloc((size_t)6 * (NBUCK + 1) * 4);
    int* gcur     = (int*)alloc((size_t)6 * NBUCK * 4);
    int* col      = (int*)alloc((size_t)3 * E * 4);
    unsigned* pairs = (unsigned*)alloc((size_t)3 * E * 4);
    unsigned char* sbytes = (unsigned char*)alloc((size_t)3 * E);
    __half* T012  = (__half*)alloc((size_t)3 * N * 128 * 2);
    __half* Tp    = (__half*)alloc((size_t)3 * N * 64 * 2);
    __half* hA    = (__half*)alloc((size_t)N * 128 * 2);
    __half* hB    = (__half*)alloc((size_t)N * 128 * 2);
    __half* oA    = (__half*)alloc((size_t)N * 64 * 2);
    __half* oB    = (__half*)alloc((size_t)N * 64 * 2);
    __half* Wt    = (__half*)alloc((size_t)(3 * 128 * 128 + 3 * 128 * 64) * 2);
    (void)ws_size;

    fused0<<<6 * HB + 96, 256, 0, stream>>>(W1_rates, W1_ratedby, W1_follows,
                                            W2_rates, W2_ratedby, W2_follows, Wt,
                                            rates_src, rates_dst, ratedby_src,
                                            ratedby_dst, follows_src, follows_dst,
                                            bphist);
    bucket_scan_par<<<6, 256, 0, stream>>>(bphist, gbase, gcur);
    fused_bin<<<dim3(256, 6), 256, 0, stream>>>(rates_src, rates_dst, ratedby_src,
                                                ratedby_dst, follows_src, follows_dst,
                                                gcur, pairs, sbytes);
    fused_finish<<<dim3(NBUCK, 6), 256, 0, stream>>>(pairs, sbytes, gbase,
                                                     row_ptr, scales, col);

    gemm_l1<<<3 * GB1, 256, 0, stream>>>(feat_A, feat_B, scales, Wt, T012);
    spmm_l1<<<8 * SLNB, 256, 0, stream>>>(row_ptr, col, T012, scales,
                                          b1_rates, b1_ratedby, b1_follows,
                                          hB, hA);
    gemm_l2<<<3 * GB2, 256, 0, stream>>>(hA, hB, scales, Wt, Tp);
    spmm_l2<<<8 * SLNB, 256, 0, stream>>>(row_ptr, col, Tp, scales,
                                          b2_rates, b2_ratedby, b2_follows,
                                          oB, oA);
    score2<<<8192, 256, 0, stream>>>(oA, oB, rates_src, rates_dst,
                                     neg_src, neg_dst, (float*)d_out);
}

// Round 10
// 404.669 us; speedup vs baseline: 1.6069x; 1.6069x over previous
//
#include <hip/hip_runtime.h>
#include <hip/hip_fp16.h>
#include <cstddef>
#include <type_traits>

#define N_NODES 50000
#define E_EDGES 1000000
#define NBUCK 196          // ceil(50000/256) node-buckets (node>>8)
#define ACHUNK 3907        // ceil(E/256) edges per binning block
#define MTILES 3125        // 50000 / 16
#define HB 96              // hist blocks per index array
#define HCHUNK 10417       // ceil(E/96)
#define GB1 384            // layer-1 gemm blocks per relation
#define GB2 256            // layer-2 gemm blocks per relation
#define SLB1 256           // spmm_l1 blocks per XCD slot (grid = 8*SLB1)
#define SLB2 128           // spmm_l2 blocks per XCD slot (grid = 8*SLB2)
// IN = 128, HID = 128, OUT = 64

typedef _Float16 f16x8 __attribute__((ext_vector_type(8)));
typedef float f32x4 __attribute__((ext_vector_type(4)));

// ---------------- dispatch 1: weight cvt/transpose  ||  hist partials --------
__global__ __launch_bounds__(256) void fused0(
        const float* __restrict__ w0, const float* __restrict__ w1,
        const float* __restrict__ w2, const float* __restrict__ w3,
        const float* __restrict__ w4, const float* __restrict__ w5,
        __half* __restrict__ Wt,
        const int* __restrict__ rs, const int* __restrict__ rd,
        const int* __restrict__ bs, const int* __restrict__ bd,
        const int* __restrict__ fs, const int* __restrict__ fd,
        int* __restrict__ bphist) {
    int bx = blockIdx.x;
    if (bx < 6 * HB) {
        __shared__ int l[NBUCK];
        int arr = bx / HB, blk = bx % HB;
        const int* idx = arr == 0 ? rs : arr == 1 ? rd : arr == 2 ? bs
                       : arr == 3 ? bd : arr == 4 ? fs : fd;
        for (int b = threadIdx.x; b < NBUCK; b += 256) l[b] = 0;
        __syncthreads();
        int e0 = blk * HCHUNK;
        int e1 = e0 + HCHUNK; if (e1 > E_EDGES) e1 = E_EDGES;
        for (int i = e0 + threadIdx.x; i < e1; i += 256)
            atomicAdd(&l[((unsigned)idx[i]) >> 8], 1);
        __syncthreads();
        int* dst = bphist + (size_t)(arr * HB + blk) * NBUCK;
        for (int b = threadIdx.x; b < NBUCK; b += 256) dst[b] = l[b];
        return;
    }
    bx -= 6 * HB;
    int m = bx / 16, part = bx % 16;
    const float* W = m == 0 ? w0 : m == 1 ? w1 : m == 2 ? w2 : m == 3 ? w3 : m == 4 ? w4 : w5;
    __half* Tt = Wt + (m < 3 ? m * 16384 : 49152 + (m - 3) * 8192);
    int ncol = m < 3 ? 128 : 64;
    int tot = 128 * ncol;
    for (int i = part * 256 + threadIdx.x; i < tot; i += 16 * 256) {
        int n = i >> 7, k = i & 127;          // Wt[n][k] = W[k][n]
        Tt[i] = __float2half(W[k * ncol + n]);
    }
}

// ---------------- dispatch 2: parallel bucket scan -> gbase, gcur ------------
__global__ void bucket_scan_par(const int* __restrict__ bphist, int* __restrict__ gbase,
                                int* __restrict__ gcur) {
    int arr = blockIdx.x;   // 0..5
    int t = threadIdx.x;    // 256
    int c = 0;
    if (t < NBUCK) {
        const int* p = bphist + (size_t)arr * HB * NBUCK + t;
#pragma unroll 8
        for (int blk = 0; blk < HB; blk++) c += p[(size_t)blk * NBUCK];
    }
    int lane = t & 63, wid = t >> 6;
    __shared__ int wsum[4];
    int v = c;
#pragma unroll
    for (int o = 1; o < 64; o <<= 1) { int u = __shfl_up(v, o); if (lane >= o) v += u; }
    if (lane == 63) wsum[wid] = v;
    __syncthreads();
    int base = 0;
    for (int ww = 0; ww < wid; ww++) base += wsum[ww];
    int excl = base + v - c;
    if (t < NBUCK) {
        gbase[arr * (NBUCK + 1) + t] = excl;
        gcur[arr * NBUCK + t] = excl;
    }
    if (t == 255) gbase[arr * (NBUCK + 1) + NBUCK] = base + v;   // == E
}

// ---------------- dispatch 3: binP (y<3) || binS (y>=3) ----------------------
__global__ __launch_bounds__(256) void fused_bin(
        const int* __restrict__ rs, const int* __restrict__ rd,
        const int* __restrict__ bs, const int* __restrict__ bd,
        const int* __restrict__ fs, const int* __restrict__ fd,
        int* __restrict__ gcur, unsigned* __restrict__ pairs,
        unsigned char* __restrict__ sbytes) {
    int y = blockIdx.y;
    __shared__ int lcnt[NBUCK];
    __shared__ int lbase[NBUCK];
    int e0 = blockIdx.x * ACHUNK;
    int e1 = e0 + ACHUNK; if (e1 > E_EDGES) e1 = E_EDGES;
    for (int b = threadIdx.x; b < NBUCK; b += 256) lcnt[b] = 0;
    __syncthreads();
    if (y < 3) {
        int rel = y, arr = 2 * rel + 1;
        const int* src = rel == 0 ? rs : rel == 1 ? bs : fs;
        const int* dst = rel == 0 ? rd : rel == 1 ? bd : fd;
        for (int i = e0 + threadIdx.x; i < e1; i += 256)
            atomicAdd(&lcnt[((unsigned)dst[i]) >> 8], 1);
        __syncthreads();
        for (int b = threadIdx.x; b < NBUCK; b += 256) {
            lbase[b] = lcnt[b] ? atomicAdd(&gcur[arr * NBUCK + b], lcnt[b]) : 0;
            lcnt[b] = 0;
        }
        __syncthreads();
        unsigned* pp = pairs + (size_t)rel * E_EDGES;
        for (int i = e0 + threadIdx.x; i < e1; i += 256) {
            int d = dst[i];
            int b = ((unsigned)d) >> 8;
            int p = lbase[b] + atomicAdd(&lcnt[b], 1);
            pp[p] = ((unsigned)(d & 255) << 16) | (unsigned)src[i];
        }
    } else {
        int rel = y - 3, arr = 2 * rel;
        const int* src = rel == 0 ? rs : rel == 1 ? bs : fs;
        for (int i = e0 + threadIdx.x; i < e1; i += 256)
            atomicAdd(&lcnt[((unsigned)src[i]) >> 8], 1);
        __syncthreads();
        for (int b = threadIdx.x; b < NBUCK; b += 256) {
            lbase[b] = lcnt[b] ? atomicAdd(&gcur[arr * NBUCK + b], lcnt[b]) : 0;
            lcnt[b] = 0;
        }
        __syncthreads();
        unsigned char* sb = sbytes + (size_t)rel * E_EDGES;
        for (int i = e0 + threadIdx.x; i < e1; i += 256) {
            int s = src[i];
            int b = ((unsigned)s) >> 8;
            int p = lbase[b] + atomicAdd(&lcnt[b], 1);
            sb[p] = (unsigned char)(s & 255);
        }
    }
}

// ---------------- dispatch 4: countS (y<3) || fillB2 (y>=3) ------------------
__global__ __launch_bounds__(256) void fused_finish(
        const unsigned* __restrict__ pairs, const unsigned char* __restrict__ sbytes,
        const int* __restrict__ gbase, int* __restrict__ row_ptr,
        float* __restrict__ scales, int* __restrict__ col) {
    int y = blockIdx.y, b = blockIdx.x, t = threadIdx.x;
    __shared__ int cnt[256];
    __shared__ int rowbase[256];
    __shared__ int wsum[4];
    if (y < 3) {
        int rel = y, arr = 2 * rel;
        int p0 = gbase[arr * (NBUCK + 1) + b];
        int p1 = gbase[arr * (NBUCK + 1) + b + 1];
        const unsigned char* sb = sbytes + (size_t)rel * E_EDGES;
        cnt[t] = 0;
        __syncthreads();
        for (int i = p0 + t; i < p1; i += 256)
            atomicAdd(&cnt[sb[i]], 1);
        __syncthreads();
        int node = b * 256 + t;
        if (node < N_NODES) {
            int c = cnt[t]; if (c < 1) c = 1;
            scales[(size_t)arr * N_NODES + node] = 1.0f / sqrtf((float)c);
        }
    } else {
        int rel = y - 3, arr = 2 * rel + 1;
        int gb = gbase[arr * (NBUCK + 1) + b];
        int ge = gbase[arr * (NBUCK + 1) + b + 1];
        const unsigned* pp = pairs + (size_t)rel * E_EDGES;
        cnt[t] = 0;
        __syncthreads();
        for (int i = gb + t; i < ge; i += 256)
            atomicAdd(&cnt[pp[i] >> 16], 1);
        __syncthreads();
        int lane = t & 63, wid = t >> 6;
        int c0 = cnt[t];
        int v = c0;
#pragma unroll
        for (int o = 1; o < 64; o <<= 1) { int u = __shfl_up(v, o); if (lane >= o) v += u; }
        if (lane == 63) wsum[wid] = v;
        __syncthreads();
        int base = gb;
        for (int w = 0; w < wid; w++) base += wsum[w];
        int excl = base + v - c0;
        rowbase[t] = excl;
        int node = b * 256 + t;
        if (node <= N_NODES)
            row_ptr[(size_t)rel * (N_NODES + 1) + node] = excl;
        if (node < N_NODES) {
            int c = c0; if (c < 1) c = 1;
            scales[(size_t)arr * N_NODES + node] = 1.0f / sqrtf((float)c);
        }
        cnt[t] = 0;   // reuse as per-row cursor
        __syncthreads();
        int* cl = col + (size_t)rel * E_EDGES;
        for (int i = gb + t; i < ge; i += 256) {
            unsigned p = pp[i];
            int dl = p >> 16;
            int slot = rowbase[dl] + atomicAdd(&cnt[dl], 1);
            cl[slot] = (int)(p & 0xFFFFu);
        }
    }
}

// --------------------------------------------- MFMA GEMM body: T = diag(s)*(X@W)
// Row-major T output. C/D layout: col = lane&15, row = (lane>>4)*4 + reg.
template <int NCOL, typename XT>
__device__ __forceinline__ void gemm_body(const XT* __restrict__ X,
                                          const float* __restrict__ sc,
                                          const __half* __restrict__ Wt,
                                          __half* __restrict__ T,
                                          int bxr, int nblocks) {
    constexpr int NHALF = NCOL / 64;        // 2 for 128, 1 for 64
    int gw = bxr * 4 + ((int)threadIdx.x >> 6);
    int lane = threadIdx.x & 63;
    int half_id = gw % NHALF;
    int mstream = gw / NHALF;
    int nstreams = nblocks * 4 / NHALF;
    int l15 = lane & 15, g = lane >> 4;

    f16x8 b[4][4];
    {
        const __half* wb = Wt + ((size_t)half_id * 64 + l15) * 128 + g * 8;
#pragma unroll
        for (int nt = 0; nt < 4; nt++)
#pragma unroll
            for (int kb = 0; kb < 4; kb++)
                b[nt][kb] = *(const f16x8*)(wb + nt * 16 * 128 + kb * 32);
    }

    for (int mt = mstream; mt < MTILES; mt += nstreams) {
        int m0 = mt * 16;
        f16x8 a[4];
        if constexpr (std::is_same<XT, float>::value) {
            const float* xr = X + (size_t)(m0 + l15) * 128 + g * 8;
#pragma unroll
            for (int kb = 0; kb < 4; kb++) {
                float4 u = *(const float4*)(xr + kb * 32);
                float4 v = *(const float4*)(xr + kb * 32 + 4);
                f16x8 t;
                t[0] = (_Float16)u.x; t[1] = (_Float16)u.y;
                t[2] = (_Float16)u.z; t[3] = (_Float16)u.w;
                t[4] = (_Float16)v.x; t[5] = (_Float16)v.y;
                t[6] = (_Float16)v.z; t[7] = (_Float16)v.w;
                a[kb] = t;
            }
        } else {
            const _Float16* xr = (const _Float16*)X + (size_t)(m0 + l15) * 128 + g * 8;
#pragma unroll
            for (int kb = 0; kb < 4; kb++)
                a[kb] = *(const f16x8*)(xr + kb * 32);
        }
        f32x4 acc[4];
#pragma unroll
        for (int nt = 0; nt < 4; nt++) acc[nt] = (f32x4){0.f, 0.f, 0.f, 0.f};
#pragma unroll
        for (int kb = 0; kb < 4; kb++)
#pragma unroll
            for (int nt = 0; nt < 4; nt++)
                acc[nt] = __builtin_amdgcn_mfma_f32_16x16x32_f16(a[kb], b[nt][kb], acc[nt], 0, 0, 0);
        int mrow = m0 + g * 4;
#pragma unroll
        for (int j = 0; j < 4; j++) {
            float sj = sc[mrow + j];
            __half* tj = T + (size_t)(mrow + j) * NCOL + half_id * 64 + l15;
            tj[0]  = __float2half(acc[0][j] * sj);
            tj[16] = __float2half(acc[1][j] * sj);
            tj[32] = __float2half(acc[2][j] * sj);
            tj[48] = __float2half(acc[3][j] * sj);
        }
    }
}

// ---------------- dispatch 5: layer-1 GEMMs (3 relations) --------------------
__global__ __launch_bounds__(256) void gemm_l1(const float* __restrict__ fA,
                                               const float* __restrict__ fB,
                                               const float* __restrict__ scales,
                                               const __half* __restrict__ Wt,
                                               __half* __restrict__ T012) {
    int rel = blockIdx.x / GB1, bxr = blockIdx.x % GB1;
    const float* X = (rel == 1) ? fB : fA;
    const float* sc = scales + (rel == 0 ? 0 : rel == 1 ? 2 * N_NODES : 4 * N_NODES);
    const __half* W = Wt + rel * 16384;
    __half* T = T012 + (size_t)rel * N_NODES * 128;
    gemm_body<128, float>(X, sc, W, T, bxr, GB1);
}

// ---------------- dispatch 7: layer-2 GEMMs (3 relations) --------------------
__global__ __launch_bounds__(256) void gemm_l2(const __half* __restrict__ hA,
                                               const __half* __restrict__ hB,
                                               const float* __restrict__ scales,
                                               const __half* __restrict__ Wt,
                                               __half* __restrict__ Tp) {
    int rel = blockIdx.x / GB2, bxr = blockIdx.x % GB2;
    const __half* X = (rel == 1) ? hB : hA;
    const float* sc = scales + (rel == 0 ? 0 : rel == 1 ? 2 * N_NODES : 4 * N_NODES);
    const __half* W = Wt + 49152 + rel * 8192;
    __half* T = Tp + (size_t)rel * N_NODES * 64;
    gemm_body<64, __half>(X, sc, W, T, bxr, GB2);
}

// ---------------- dispatch 6: layer-1 SpMM, relation->XCD-group partitioned --
// slot = blockIdx&7 (round-robin block->XCD): slots 0-2 do hB rows (touch only
// T0: 12.8MB/XCD), slots 3-7 do hA dual-stream rows (T1+T2: 25.6MB/XCD).
// Full 64-lane row gathers (R7-proven structure).
__global__ __launch_bounds__(256) void spmm_l1(
        const int* __restrict__ row_ptr, const int* __restrict__ col,
        const __half* __restrict__ T012, const float* __restrict__ scales,
        const float* __restrict__ b1r, const float* __restrict__ b1rb,
        const float* __restrict__ b1f,
        __half* __restrict__ hB, __half* __restrict__ hA) {
    int slot = blockIdx.x & 7;
    int w = (blockIdx.x >> 3) * 4 + ((int)threadIdx.x >> 6);
    const int NW = SLB1 * 4;   // waves per slot
    int lane = threadIdx.x & 63;
    unsigned loff = (unsigned)lane << 2;
    const char* T0 = (const char*)T012;
    const char* T1 = T0 + (size_t)N_NODES * 256;
    const char* T2 = T1 + (size_t)N_NODES * 256;
#define LDT(B, c) __half22float2(*(const __half2*)((B) + (((unsigned)(c) << 8) + loff)))
    if (slot < 3) {
        for (int p = slot + 3 * w; p < N_NODES / 2; p += 3 * NW) {
            const int* cl = col;
            int rowA = p * 2, rowB = rowA + 1;
            int eA = row_ptr[rowA], EA = row_ptr[rowA + 1];
            int eB = EA, EB = row_ptr[rowB + 1];
            float axA = 0.f, ayA = 0.f, axB = 0.f, ayB = 0.f;
            while (eA + 4 <= EA && eB + 4 <= EB) {
                int a0 = cl[eA], a1 = cl[eA+1], a2 = cl[eA+2], a3 = cl[eA+3];
                int b0 = cl[eB], b1 = cl[eB+1], b2 = cl[eB+2], b3 = cl[eB+3];
                float2 v0 = LDT(T0, a0), v1 = LDT(T0, a1), v2 = LDT(T0, a2), v3 = LDT(T0, a3);
                float2 u0 = LDT(T0, b0), u1 = LDT(T0, b1), u2 = LDT(T0, b2), u3 = LDT(T0, b3);
                axA += (v0.x + v1.x) + (v2.x + v3.x); ayA += (v0.y + v1.y) + (v2.y + v3.y);
                axB += (u0.x + u1.x) + (u2.x + u3.x); ayB += (u0.y + u1.y) + (u2.y + u3.y);
                eA += 4; eB += 4;
            }
            while (eA + 4 <= EA) {
                int a0 = cl[eA], a1 = cl[eA+1], a2 = cl[eA+2], a3 = cl[eA+3];
                float2 v0 = LDT(T0, a0), v1 = LDT(T0, a1), v2 = LDT(T0, a2), v3 = LDT(T0, a3);
                axA += (v0.x + v1.x) + (v2.x + v3.x); ayA += (v0.y + v1.y) + (v2.y + v3.y);
                eA += 4;
            }
            while (eB + 4 <= EB) {
                int b0 = cl[eB], b1 = cl[eB+1], b2 = cl[eB+2], b3 = cl[eB+3];
                float2 u0 = LDT(T0, b0), u1 = LDT(T0, b1), u2 = LDT(T0, b2), u3 = LDT(T0, b3);
                axB += (u0.x + u1.x) + (u2.x + u3.x); ayB += (u0.y + u1.y) + (u2.y + u3.y);
                eB += 4;
            }
            while (eA < EA && eB < EB) {
                float2 v = LDT(T0, cl[eA]), u = LDT(T0, cl[eB]);
                axA += v.x; ayA += v.y; axB += u.x; ayB += u.y;
                eA++; eB++;
            }
            for (; eA < EA; eA++) { float2 v = LDT(T0, cl[eA]); axA += v.x; ayA += v.y; }
            for (; eB < EB; eB++) { float2 v = LDT(T0, cl[eB]); axB += v.x; ayB += v.y; }
            float bx = b1r[2 * lane], by = b1r[2 * lane + 1];
            float sA = scales[N_NODES + rowA], sB = scales[N_NODES + rowB];
            float ox = fmaxf(fmaf(axA, sA, bx), 0.f), oy = fmaxf(fmaf(ayA, sA, by), 0.f);
            *(__half2*)(hB + (size_t)rowA * 128 + 2 * lane) = __floats2half2_rn(ox, oy);
            ox = fmaxf(fmaf(axB, sB, bx), 0.f); oy = fmaxf(fmaf(ayB, sB, by), 0.f);
            *(__half2*)(hB + (size_t)rowB * 128 + 2 * lane) = __floats2half2_rn(ox, oy);
        }
    } else {
        const int* rp1 = row_ptr + (N_NODES + 1);
        const int* rp2 = row_ptr + 2 * (N_NODES + 1);
        const int* cl1 = col + E_EDGES;
        const int* cl2 = col + 2 * (size_t)E_EDGES;
        for (int r = (slot - 3) + 5 * w; r < N_NODES; r += 5 * NW) {
            int e1 = rp1[r], E1 = rp1[r + 1];
            int e2 = rp2[r], E2 = rp2[r + 1];
            float a1x = 0.f, a1y = 0.f, a2x = 0.f, a2y = 0.f;
            while (e1 + 4 <= E1 && e2 + 4 <= E2) {
                int a0 = cl1[e1], a1 = cl1[e1+1], a2 = cl1[e1+2], a3 = cl1[e1+3];
                int b0 = cl2[e2], b1 = cl2[e2+1], b2 = cl2[e2+2], b3 = cl2[e2+3];
                float2 v0 = LDT(T1, a0), v1 = LDT(T1, a1), v2 = LDT(T1, a2), v3 = LDT(T1, a3);
                float2 u0 = LDT(T2, b0), u1 = LDT(T2, b1), u2 = LDT(T2, b2), u3 = LDT(T2, b3);
                a1x += (v0.x + v1.x) + (v2.x + v3.x); a1y += (v0.y + v1.y) + (v2.y + v3.y);
                a2x += (u0.x + u1.x) + (u2.x + u3.x); a2y += (u0.y + u1.y) + (u2.y + u3.y);
                e1 += 4; e2 += 4;
            }
            while (e1 + 4 <= E1) {
                int a0 = cl1[e1], a1 = cl1[e1+1], a2 = cl1[e1+2], a3 = cl1[e1+3];
                float2 v0 = LDT(T1, a0), v1 = LDT(T1, a1), v2 = LDT(T1, a2), v3 = LDT(T1, a3);
                a1x += (v0.x + v1.x) + (v2.x + v3.x); a1y += (v0.y + v1.y) + (v2.y + v3.y);
                e1 += 4;
            }
            while (e2 + 4 <= E2) {
                int b0 = cl2[e2], b1 = cl2[e2+1], b2 = cl2[e2+2], b3 = cl2[e2+3];
                float2 u0 = LDT(T2, b0), u1 = LDT(T2, b1), u2 = LDT(T2, b2), u3 = LDT(T2, b3);
                a2x += (u0.x + u1.x) + (u2.x + u3.x); a2y += (u0.y + u1.y) + (u2.y + u3.y);
                e2 += 4;
            }
            while (e1 < E1 && e2 < E2) {
                float2 v = LDT(T1, cl1[e1]), u = LDT(T2, cl2[e2]);
                a1x += v.x; a1y += v.y; a2x += u.x; a2y += u.y;
                e1++; e2++;
            }
            for (; e1 < E1; e1++) { float2 v = LDT(T1, cl1[e1]); a1x += v.x; a1y += v.y; }
            for (; e2 < E2; e2++) { float2 v = LDT(T2, cl2[e2]); a2x += v.x; a2y += v.y; }
            float s1 = scales[3 * N_NODES + r], s2 = scales[5 * N_NODES + r];
            float ox = a1x * s1 + a2x * s2 + b1rb[2 * lane] + b1f[2 * lane];
            float oy = a1y * s1 + a2y * s2 + b1rb[2 * lane + 1] + b1f[2 * lane + 1];
            ox = fmaxf(ox, 0.f); oy = fmaxf(oy, 0.f);
            *(__half2*)(hA + (size_t)r * 128 + 2 * lane) = __floats2half2_rn(ox, oy);
        }
    }
#undef LDT
}

// ---------------- dispatch 8: layer-2 SpMM, same partitioning (32-lane) ------
__global__ __launch_bounds__(256) void spmm_l2(
        const int* __restrict__ row_ptr, const int* __restrict__ col,
        const __half* __restrict__ Tp, const float* __restrict__ scales,
        const float* __restrict__ b2r, const float* __restrict__ b2rb,
        const float* __restrict__ b2f,
        __half* __restrict__ oB, __half* __restrict__ oA) {
    int slot = blockIdx.x & 7;
    int g = (blockIdx.x >> 3) * 8 + ((int)threadIdx.x >> 5);
    const int NG = SLB2 * 8;   // groups per slot
    int l2 = threadIdx.x & 31;
    unsigned loff = (unsigned)l2 << 2;
    const char* T0 = (const char*)Tp;
    const char* T1 = T0 + (size_t)N_NODES * 128;
    const char* T2 = T1 + (size_t)N_NODES * 128;
#define LDT(B, c) __half22float2(*(const __half2*)((B) + (((unsigned)(c) << 7) + loff)))
    if (slot < 3) {
        for (int p = slot + 3 * g; p < N_NODES / 2; p += 3 * NG) {
            const int* cl = col;
            int rowA = p * 2, rowB = rowA + 1;
            int eA = row_ptr[rowA], EA = row_ptr[rowA + 1];
            int eB = EA, EB = row_ptr[rowB + 1];
            float axA = 0.f, ayA = 0.f, axB = 0.f, ayB = 0.f;
            while (eA + 4 <= EA && eB + 4 <= EB) {
                int a0 = cl[eA], a1 = cl[eA+1], a2 = cl[eA+2], a3 = cl[eA+3];
                int b0 = cl[eB], b1 = cl[eB+1], b2 = cl[eB+2], b3 = cl[eB+3];
                float2 v0 = LDT(T0, a0), v1 = LDT(T0, a1), v2 = LDT(T0, a2), v3 = LDT(T0, a3);
                float2 u0 = LDT(T0, b0), u1 = LDT(T0, b1), u2 = LDT(T0, b2), u3 = LDT(T0, b3);
                axA += (v0.x + v1.x) + (v2.x + v3.x); ayA += (v0.y + v1.y) + (v2.y + v3.y);
                axB += (u0.x + u1.x) + (u2.x + u3.x); ayB += (u0.y + u1.y) + (u2.y + u3.y);
                eA += 4; eB += 4;
            }
            while (eA + 4 <= EA) {
                int a0 = cl[eA], a1 = cl[eA+1], a2 = cl[eA+2], a3 = cl[eA+3];
                float2 v0 = LDT(T0, a0), v1 = LDT(T0, a1), v2 = LDT(T0, a2), v3 = LDT(T0, a3);
                axA += (v0.x + v1.x) + (v2.x + v3.x); ayA += (v0.y + v1.y) + (v2.y + v3.y);
                eA += 4;
            }
            while (eB + 4 <= EB) {
                int b0 = cl[eB], b1 = cl[eB+1], b2 = cl[eB+2], b3 = cl[eB+3];
                float2 u0 = LDT(T0, b0), u1 = LDT(T0, b1), u2 = LDT(T0, b2), u3 = LDT(T0, b3);
                axB += (u0.x + u1.x) + (u2.x + u3.x); ayB += (u0.y + u1.y) + (u2.y + u3.y);
                eB += 4;
            }
            while (eA < EA && eB < EB) {
                float2 v = LDT(T0, cl[eA]), u = LDT(T0, cl[eB]);
                axA += v.x; ayA += v.y; axB += u.x; ayB += u.y;
                eA++; eB++;
            }
            for (; eA < EA; eA++) { float2 v = LDT(T0, cl[eA]); axA += v.x; ayA += v.y; }
            for (; eB < EB; eB++) { float2 v = LDT(T0, cl[eB]); axB += v.x; ayB += v.y; }
            float bx = b2r[2 * l2], by = b2r[2 * l2 + 1];
            float sA = scales[N_NODES + rowA], sB = scales[N_NODES + rowB];
            *(__half2*)(oB + (size_t)rowA * 64 + 2 * l2) =
                __floats2half2_rn(fmaf(axA, sA, bx), fmaf(ayA, sA, by));
            *(__half2*)(oB + (size_t)rowB * 64 + 2 * l2) =
                __floats2half2_rn(fmaf(axB, sB, bx), fmaf(ayB, sB, by));
        }
    } else {
        const int* rp1 = row_ptr + (N_NODES + 1);
        const int* rp2 = row_ptr + 2 * (N_NODES + 1);
        const int* cl1 = col + E_EDGES;
        const int* cl2 = col + 2 * (size_t)E_EDGES;
        for (int r = (slot - 3) + 5 * g; r < N_NODES; r += 5 * NG) {
            int e1 = rp1[r], E1 = rp1[r + 1];
            int e2 = rp2[r], E2 = rp2[r + 1];
            float a1x = 0.f, a1y = 0.f, a2x = 0.f, a2y = 0.f;
            while (e1 + 4 <= E1 && e2 + 4 <= E2) {
                int a0 = cl1[e1], a1 = cl1[e1+1], a2 = cl1[e1+2], a3 = cl1[e1+3];
                int b0 = cl2[e2], b1 = cl2[e2+1], b2 = cl2[e2+2], b3 = cl2[e2+3];
                float2 v0 = LDT(T1, a0), v1 = LDT(T1, a1), v2 = LDT(T1, a2), v3 = LDT(T1, a3);
                float2 u0 = LDT(T2, b0), u1 = LDT(T2, b1), u2 = LDT(T2, b2), u3 = LDT(T2, b3);
                a1x += (v0.x + v1.x) + (v2.x + v3.x); a1y += (v0.y + v1.y) + (v2.y + v3.y);
                a2x += (u0.x + u1.x) + (u2.x + u3.x); a2y += (u0.y + u1.y) + (u2.y + u3.y);
                e1 += 4; e2 += 4;
            }
            while (e1 + 4 <= E1) {
                int a0 = cl1[e1], a1 = cl1[e1+1], a2 = cl1[e1+2], a3 = cl1[e1+3];
                float2 v0 = LDT(T1, a0), v1 = LDT(T1, a1), v2 = LDT(T1, a2), v3 = LDT(T1, a3);
                a1x += (v0.x + v1.x) + (v2.x + v3.x); a1y += (v0.y + v1.y) + (v2.y + v3.y);
                e1 += 4;
            }
            while (e2 + 4 <= E2) {
                int b0 = cl2[e2], b1 = cl2[e2+1], b2 = cl2[e2+2], b3 = cl2[e2+3];
                float2 u0 = LDT(T2, b0), u1 = LDT(T2, b1), u2 = LDT(T2, b2), u3 = LDT(T2, b3);
                a2x += (u0.x + u1.x) + (u2.x + u3.x); a2y += (u0.y + u1.y) + (u2.y + u3.y);
                e2 += 4;
            }
            while (e1 < E1 && e2 < E2) {
                float2 v = LDT(T1, cl1[e1]), u = LDT(T2, cl2[e2]);
                a1x += v.x; a1y += v.y; a2x += u.x; a2y += u.y;
                e1++; e2++;
            }
            for (; e1 < E1; e1++) { float2 v = LDT(T1, cl1[e1]); a1x += v.x; a1y += v.y; }
            for (; e2 < E2; e2++) { float2 v = LDT(T2, cl2[e2]); a2x += v.x; a2y += v.y; }
            float s1 = scales[3 * N_NODES + r], s2 = scales[5 * N_NODES + r];
            float ox = a1x * s1 + a2x * s2 + b2rb[2 * l2] + b2f[2 * l2];
            float oy = a1y * s1 + a2y * s2 + b2rb[2 * l2 + 1] + b2f[2 * l2 + 1];
            *(__half2*)(oA + (size_t)r * 64 + 2 * l2) = __floats2half2_rn(ox, oy);
        }
    }
#undef LDT
}

// ---------------- dispatch 9: scoring (pos + neg fused) ----------------------
__global__ __launch_bounds__(256) void score2(const __half* __restrict__ oA,
                                              const __half* __restrict__ oB,
                                              const int* __restrict__ ps,
                                              const int* __restrict__ pd,
                                              const int* __restrict__ ns,
                                              const int* __restrict__ nd,
                                              float* __restrict__ out) {
    int g = (blockIdx.x * blockDim.x + threadIdx.x) >> 4;
    int l = threadIdx.x & 15;
    int ng = (gridDim.x * blockDim.x) >> 4;
    const char* A = (const char*)oA;
    const char* B = (const char*)oB;
    unsigned loff = (unsigned)l << 3;   // 4 halves per lane
#define SCORE_LOOP(SRC, DST, OUT)                                               \
    for (int e0 = g * 2; e0 < E_EDGES; e0 += ng * 2) {                          \
        int e1 = e0 + 1;                                                        \
        int s0 = SRC[e0], d0 = DST[e0], s1 = SRC[e1], d1 = DST[e1];             \
        union { uint2 u; __half2 h[2]; } a0, b0, a1, b1;                        \
        a0.u = *(const uint2*)(A + (((unsigned)s0 << 7) + loff));               \
        b0.u = *(const uint2*)(B + (((unsigned)d0 << 7) + loff));               \
        a1.u = *(const uint2*)(A + (((unsigned)s1 << 7) + loff));               \
        b1.u = *(const uint2*)(B + (((unsigned)d1 << 7) + loff));               \
        float2 fa, fb;                                                          \
        fa = __half22float2(a0.h[0]); fb = __half22float2(b0.h[0]);             \
        float p0 = fa.x * fb.x + fa.y * fb.y;                                   \
        fa = __half22float2(a0.h[1]); fb = __half22float2(b0.h[1]);             \
        p0 += fa.x * fb.x + fa.y * fb.y;                                        \
        fa = __half22float2(a1.h[0]); fb = __half22float2(b1.h[0]);             \
        float p1 = fa.x * fb.x + fa.y * fb.y;                                   \
        fa = __half22float2(a1.h[1]); fb = __half22float2(b1.h[1]);             \
        p1 += fa.x * fb.x + fa.y * fb.y;                                        \
        p0 += __shfl_xor(p0, 8); p1 += __shfl_xor(p1, 8);                       \
        p0 += __shfl_xor(p0, 4); p1 += __shfl_xor(p1, 4);                       \
        p0 += __shfl_xor(p0, 2); p1 += __shfl_xor(p1, 2);                       \
        p0 += __shfl_xor(p0, 1); p1 += __shfl_xor(p1, 1);                       \
        if (l == 0) { OUT[e0] = p0; OUT[e1] = p1; }                             \
    }
    SCORE_LOOP(ps, pd, out)
    float* outn = out + E_EDGES;
    SCORE_LOOP(ns, nd, outn)
#undef SCORE_LOOP
}

// ---------------------------------------------------------------------------
extern "C" void kernel_launch(void* const* d_in, const int* in_sizes, int n_in,
                              void* d_out, int out_size, void* d_ws, size_t ws_size,
                              hipStream_t stream) {
    const float* feat_A     = (const float*)d_in[0];
    const float* feat_B     = (const float*)d_in[1];
    const int* rates_src    = (const int*)d_in[2];
    const int* rates_dst    = (const int*)d_in[3];
    const int* ratedby_src  = (const int*)d_in[4];
    const int* ratedby_dst  = (const int*)d_in[5];
    const int* follows_src  = (const int*)d_in[6];
    const int* follows_dst  = (const int*)d_in[7];
    const int* neg_src      = (const int*)d_in[8];
    const int* neg_dst      = (const int*)d_in[9];
    const float* W1_rates   = (const float*)d_in[10];
    const float* b1_rates   = (const float*)d_in[11];
    const float* W1_ratedby = (const float*)d_in[12];
    const float* b1_ratedby = (const float*)d_in[13];
    const float* W1_follows = (const float*)d_in[14];
    const float* b1_follows = (const float*)d_in[15];
    const float* W2_rates   = (const float*)d_in[16];
    const float* b2_rates   = (const float*)d_in[17];
    const float* W2_ratedby = (const float*)d_in[18];
    const float* b2_ratedby = (const float*)d_in[19];
    const float* W2_follows = (const float*)d_in[20];
    const float* b2_follows = (const float*)d_in[21];

    const int N = N_NODES, E = E_EDGES;

    char* ws = (char*)d_ws;
    size_t off = 0;
    auto alloc = [&](size_t bytes) -> void* {
        void* p = ws + off;
        off += (bytes + 255) & ~(size_t)255;
        return p;
    };
    float* scales = (float*)alloc((size_t)6 * N * 4);
    int* row_ptr  = (int*)alloc((size_t)3 * (N + 1) * 4);
    int* bphist   = (int*)alloc((size_t)6 * HB * NBUCK * 4);
    int* gbase    = (int*)alloc((size_t)6 * (NBUCK + 1) * 4);
    int* gcur     = (int*)alloc((size_t)6 * NBUCK * 4);
    int* col      = (int*)alloc((size_t)3 * E * 4);
    unsigned* pairs = (unsigned*)alloc((size_t)3 * E * 4);
    unsigned char* sbytes = (unsigned char*)alloc((size_t)3 * E);
    __half* T012  = (__half*)alloc((size_t)3 * N * 128 * 2);
    __half* Tp    = (__half*)alloc((size_t)3 * N * 64 * 2);
    __half* hA    = (__half*)alloc((size_t)N * 128 * 2);
    __half* hB    = (__half*)alloc((size_t)N * 128 * 2);
    __half* oA    = (__half*)alloc((size_t)N * 64 * 2);
    __half* oB    = (__half*)alloc((size_t)N * 64 * 2);
    __half* Wt    = (__half*)alloc((size_t)(3 * 128 * 128 + 3 * 128 * 64) * 2);
    (void)ws_size;

    fused0<<<6 * HB + 96, 256, 0, stream>>>(W1_rates, W1_ratedby, W1_follows,
                                            W2_rates, W2_ratedby, W2_follows, Wt,
                                            rates_src, rates_dst, ratedby_src,
                                            ratedby_dst, follows_src, follows_dst,
                                            bphist);
    bucket_scan_par<<<6, 256, 0, stream>>>(bphist, gbase, gcur);
    fused_bin<<<dim3(256, 6), 256, 0, stream>>>(rates_src, rates_dst, ratedby_src,
                                                ratedby_dst, follows_src, follows_dst,
                                                gcur, pairs, sbytes);
    fused_finish<<<dim3(NBUCK, 6), 256, 0, stream>>>(pairs, sbytes, gbase,
                                                     row_ptr, scales, col);

    gemm_l1<<<3 * GB1, 256, 0, stream>>>(feat_A, feat_B, scales, Wt, T012);
    spmm_l1<<<8 * SLB1, 256, 0, stream>>>(row_ptr, col, T012, scales,
                                          b1_rates, b1_ratedby, b1_follows,
                                          hB, hA);
    gemm_l2<<<3 * GB2, 256, 0, stream>>>(hA, hB, scales, Wt, Tp);
    spmm_l2<<<8 * SLB2, 256, 0, stream>>>(row_ptr, col, Tp, scales,
                                          b2_rates, b2_ratedby, b2_follows,
                                          oB, oA);
    score2<<<8192, 256, 0, stream>>>(oA, oB, rates_src, rates_dst,
                                     neg_src, neg_dst, (float*)d_out);
}

// Round 11
// 402.224 us; speedup vs baseline: 1.6167x; 1.0061x over previous
//
#include <hip/hip_runtime.h>
#include <hip/hip_fp16.h>
#include <cstddef>

#define N_NODES 50000
#define E_EDGES 1000000
#define NBUCK 196          // ceil(50000/256) node-buckets (node>>8)
#define ACHUNK 3907        // ceil(E/256) edges per binning block
#define MTILES 3125        // 50000 / 16
#define HB 96              // hist blocks per index array
#define HCHUNK 10417       // ceil(E/96)
// IN = 128, HID = 128, OUT = 64

typedef _Float16 f16x8 __attribute__((ext_vector_type(8)));
typedef float f32x4 __attribute__((ext_vector_type(4)));

// Wt layout (halves): [0,16384) Wt0 = W1_rates^T [n*128+k]
//                     [16384,49152) WtC = [W1_ratedby | W1_follows]^T [n*256 + k], k<128 rb, k>=128 f
//                     [49152,73728) Wt2 = W2_{rates,ratedby,follows}^T [rel*8192 + n*128+k]

// ---------------- dispatch 1: hist partials || weight cvt || feat->fp16 ------
__global__ __launch_bounds__(256) void fused0(
        const float* __restrict__ w1r, const float* __restrict__ w1rb,
        const float* __restrict__ w1f, const float* __restrict__ w2r,
        const float* __restrict__ w2rb, const float* __restrict__ w2f,
        __half* __restrict__ Wt,
        const float* __restrict__ fA, const float* __restrict__ fB,
        __half* __restrict__ XAh, __half* __restrict__ XBh,
        const int* __restrict__ rs, const int* __restrict__ rd,
        const int* __restrict__ bs, const int* __restrict__ bd,
        const int* __restrict__ fs, const int* __restrict__ fd,
        int* __restrict__ bphist) {
    int bx = blockIdx.x;
    if (bx < 6 * HB) {
        __shared__ int l[NBUCK];
        int arr = bx / HB, blk = bx % HB;
        const int* idx = arr == 0 ? rs : arr == 1 ? rd : arr == 2 ? bs
                       : arr == 3 ? bd : arr == 4 ? fs : fd;
        for (int b = threadIdx.x; b < NBUCK; b += 256) l[b] = 0;
        __syncthreads();
        int e0 = blk * HCHUNK;
        int e1 = e0 + HCHUNK; if (e1 > E_EDGES) e1 = E_EDGES;
        for (int i = e0 + threadIdx.x; i < e1; i += 256)
            atomicAdd(&l[((unsigned)idx[i]) >> 8], 1);
        __syncthreads();
        int* dst = bphist + (size_t)(arr * HB + blk) * NBUCK;
        for (int b = threadIdx.x; b < NBUCK; b += 256) dst[b] = l[b];
        return;
    }
    bx -= 6 * HB;
    if (bx < 96) {
        int m = bx / 16, part = bx % 16;
        if (m == 0) {
            for (int i = part * 256 + threadIdx.x; i < 16384; i += 4096) {
                int n = i >> 7, k = i & 127;
                Wt[i] = __float2half(w1r[k * 128 + n]);
            }
        } else if (m == 1 || m == 2) {
            const float* W = (m == 1) ? w1rb : w1f;
            int koff = (m == 2) ? 128 : 0;
            for (int i = part * 256 + threadIdx.x; i < 16384; i += 4096) {
                int n = i >> 7, k = i & 127;
                Wt[16384 + n * 256 + koff + k] = __float2half(W[k * 128 + n]);
            }
        } else {
            const float* W = m == 3 ? w2r : m == 4 ? w2rb : w2f;
            __half* dst = Wt + 49152 + (m - 3) * 8192;
            for (int i = part * 256 + threadIdx.x; i < 8192; i += 4096) {
                int n = i >> 7, k = i & 127;
                dst[i] = __float2half(W[k * 64 + n]);
            }
        }
        return;
    }
    bx -= 96;   // 256 blocks: convert feats to fp16 (float4 -> 4 halves)
    for (int q = bx * 256 + threadIdx.x; q < 3200000; q += 256 * 256) {
        bool isA = q < 1600000;
        int qq = isA ? q : q - 1600000;
        float4 v = ((const float4*)(isA ? fA : fB))[qq];
        union { __half2 h[2]; uint2 u; } cv;
        cv.h[0] = __floats2half2_rn(v.x, v.y);
        cv.h[1] = __floats2half2_rn(v.z, v.w);
        ((uint2*)(isA ? XAh : XBh))[qq] = cv.u;
    }
}

// ---------------- dispatch 2: parallel bucket scan -> gbase, gcur ------------
__global__ void bucket_scan_par(const int* __restrict__ bphist, int* __restrict__ gbase,
                                int* __restrict__ gcur) {
    int arr = blockIdx.x;
    int t = threadIdx.x;
    int c = 0;
    if (t < NBUCK) {
        const int* p = bphist + (size_t)arr * HB * NBUCK + t;
#pragma unroll 8
        for (int blk = 0; blk < HB; blk++) c += p[(size_t)blk * NBUCK];
    }
    int lane = t & 63, wid = t >> 6;
    __shared__ int wsum[4];
    int v = c;
#pragma unroll
    for (int o = 1; o < 64; o <<= 1) { int u = __shfl_up(v, o); if (lane >= o) v += u; }
    if (lane == 63) wsum[wid] = v;
    __syncthreads();
    int base = 0;
    for (int ww = 0; ww < wid; ww++) base += wsum[ww];
    int excl = base + v - c;
    if (t < NBUCK) {
        gbase[arr * (NBUCK + 1) + t] = excl;
        gcur[arr * NBUCK + t] = excl;
    }
    if (t == 255) gbase[arr * (NBUCK + 1) + NBUCK] = base + v;
}

// ---------------- dispatch 3: binP (y<3) || binS (y>=3) ----------------------
__global__ __launch_bounds__(256) void fused_bin(
        const int* __restrict__ rs, const int* __restrict__ rd,
        const int* __restrict__ bs, const int* __restrict__ bd,
        const int* __restrict__ fs, const int* __restrict__ fd,
        int* __restrict__ gcur, unsigned* __restrict__ pairs,
        unsigned char* __restrict__ sbytes) {
    int y = blockIdx.y;
    __shared__ int lcnt[NBUCK];
    __shared__ int lbase[NBUCK];
    int e0 = blockIdx.x * ACHUNK;
    int e1 = e0 + ACHUNK; if (e1 > E_EDGES) e1 = E_EDGES;
    for (int b = threadIdx.x; b < NBUCK; b += 256) lcnt[b] = 0;
    __syncthreads();
    if (y < 3) {
        int rel = y, arr = 2 * rel + 1;
        const int* src = rel == 0 ? rs : rel == 1 ? bs : fs;
        const int* dst = rel == 0 ? rd : rel == 1 ? bd : fd;
        for (int i = e0 + threadIdx.x; i < e1; i += 256)
            atomicAdd(&lcnt[((unsigned)dst[i]) >> 8], 1);
        __syncthreads();
        for (int b = threadIdx.x; b < NBUCK; b += 256) {
            lbase[b] = lcnt[b] ? atomicAdd(&gcur[arr * NBUCK + b], lcnt[b]) : 0;
            lcnt[b] = 0;
        }
        __syncthreads();
        unsigned* pp = pairs + (size_t)rel * E_EDGES;
        for (int i = e0 + threadIdx.x; i < e1; i += 256) {
            int d = dst[i];
            int b = ((unsigned)d) >> 8;
            int p = lbase[b] + atomicAdd(&lcnt[b], 1);
            pp[p] = ((unsigned)(d & 255) << 16) | (unsigned)src[i];
        }
    } else {
        int rel = y - 3, arr = 2 * rel;
        const int* src = rel == 0 ? rs : rel == 1 ? bs : fs;
        for (int i = e0 + threadIdx.x; i < e1; i += 256)
            atomicAdd(&lcnt[((unsigned)src[i]) >> 8], 1);
        __syncthreads();
        for (int b = threadIdx.x; b < NBUCK; b += 256) {
            lbase[b] = lcnt[b] ? atomicAdd(&gcur[arr * NBUCK + b], lcnt[b]) : 0;
            lcnt[b] = 0;
        }
        __syncthreads();
        unsigned char* sb = sbytes + (size_t)rel * E_EDGES;
        for (int i = e0 + threadIdx.x; i < e1; i += 256) {
            int s = src[i];
            int b = ((unsigned)s) >> 8;
            int p = lbase[b] + atomicAdd(&lcnt[b], 1);
            sb[p] = (unsigned char)(s & 255);
        }
    }
}

// ---------------- dispatch 4: countS (y<3) || fillB2 (y>=3), u16 col ---------
__global__ __launch_bounds__(256) void fused_finish(
        const unsigned* __restrict__ pairs, const unsigned char* __restrict__ sbytes,
        const int* __restrict__ gbase, int* __restrict__ row_ptr,
        float* __restrict__ scales, unsigned short* __restrict__ col) {
    int y = blockIdx.y, b = blockIdx.x, t = threadIdx.x;
    __shared__ int cnt[256];
    __shared__ int rowbase[256];
    __shared__ int wsum[4];
    if (y < 3) {
        int rel = y, arr = 2 * rel;
        int p0 = gbase[arr * (NBUCK + 1) + b];
        int p1 = gbase[arr * (NBUCK + 1) + b + 1];
        const unsigned char* sb = sbytes + (size_t)rel * E_EDGES;
        cnt[t] = 0;
        __syncthreads();
        for (int i = p0 + t; i < p1; i += 256)
            atomicAdd(&cnt[sb[i]], 1);
        __syncthreads();
        int node = b * 256 + t;
        if (node < N_NODES) {
            int c = cnt[t]; if (c < 1) c = 1;
            scales[(size_t)arr * N_NODES + node] = 1.0f / sqrtf((float)c);
        }
    } else {
        int rel = y - 3, arr = 2 * rel + 1;
        int gb = gbase[arr * (NBUCK + 1) + b];
        int ge = gbase[arr * (NBUCK + 1) + b + 1];
        const unsigned* pp = pairs + (size_t)rel * E_EDGES;
        cnt[t] = 0;
        __syncthreads();
        for (int i = gb + t; i < ge; i += 256)
            atomicAdd(&cnt[pp[i] >> 16], 1);
        __syncthreads();
        int lane = t & 63, wid = t >> 6;
        int c0 = cnt[t];
        int v = c0;
#pragma unroll
        for (int o = 1; o < 64; o <<= 1) { int u = __shfl_up(v, o); if (lane >= o) v += u; }
        if (lane == 63) wsum[wid] = v;
        __syncthreads();
        int base = gb;
        for (int w = 0; w < wid; w++) base += wsum[w];
        int excl = base + v - c0;
        rowbase[t] = excl;
        int node = b * 256 + t;
        if (node <= N_NODES)
            row_ptr[(size_t)rel * (N_NODES + 1) + node] = excl;
        if (node < N_NODES) {
            int c = c0; if (c < 1) c = 1;
            scales[(size_t)arr * N_NODES + node] = 1.0f / sqrtf((float)c);
        }
        cnt[t] = 0;
        __syncthreads();
        unsigned short* cl = col + (size_t)rel * E_EDGES;
        for (int i = gb + t; i < ge; i += 256) {
            unsigned p = pp[i];
            int dl = p >> 16;
            int slot = rowbase[dl] + atomicAdd(&cnt[dl], 1);
            cl[slot] = (unsigned short)(p & 0xFFFFu);
        }
    }
}

// ---------------- dispatch 5: layer-1 aggregation (gathers raw fp16 feats) ---
// item t<25000: rates row-pair (dst B): agg0[row] = s_in1[row]*sum s0[c]*XAh[c]
// item >=25000: row r (dst A), dual-stream: aggA[r][0:128)=s3[r]*sum s2[c]*XBh[c]
//                                           aggA[r][128:256)=s5[r]*sum s4[c]*XAh[c]
__global__ __launch_bounds__(256) void spmm_l1(
        const int* __restrict__ row_ptr, const unsigned short* __restrict__ col,
        const __half* __restrict__ XAh, const __half* __restrict__ XBh,
        const float* __restrict__ scales,
        __half* __restrict__ agg0, __half* __restrict__ aggA) {
    int t = (blockIdx.x * blockDim.x + threadIdx.x) >> 6;
    int lane = threadIdx.x & 63;
    unsigned loff = (unsigned)lane << 2;
    const char* XA = (const char*)XAh;
    const char* XB = (const char*)XBh;
#define LDX(B, c) __half22float2(*(const __half2*)((B) + (((unsigned)(c) << 8) + loff)))
    if (t < 25000) {
        const unsigned short* cl = col;
        const float* se = scales;            // rates_src out-scales
        int rowA = t * 2, rowB = rowA + 1;
        int eA = row_ptr[rowA], EA = row_ptr[rowA + 1];
        int eB = EA, EB = row_ptr[rowB + 1];
        float axA = 0.f, ayA = 0.f, axB = 0.f, ayB = 0.f;
        while (eA + 4 <= EA && eB + 4 <= EB) {
            int a0 = cl[eA], a1 = cl[eA+1], a2 = cl[eA+2], a3 = cl[eA+3];
            int b0 = cl[eB], b1 = cl[eB+1], b2 = cl[eB+2], b3 = cl[eB+3];
            float sa0 = se[a0], sa1 = se[a1], sa2 = se[a2], sa3 = se[a3];
            float sb0 = se[b0], sb1 = se[b1], sb2 = se[b2], sb3 = se[b3];
            float2 v0 = LDX(XA, a0), v1 = LDX(XA, a1), v2 = LDX(XA, a2), v3 = LDX(XA, a3);
            float2 u0 = LDX(XA, b0), u1 = LDX(XA, b1), u2 = LDX(XA, b2), u3 = LDX(XA, b3);
            axA = fmaf(sa0, v0.x, fmaf(sa1, v1.x, fmaf(sa2, v2.x, fmaf(sa3, v3.x, axA))));
            ayA = fmaf(sa0, v0.y, fmaf(sa1, v1.y, fmaf(sa2, v2.y, fmaf(sa3, v3.y, ayA))));
            axB = fmaf(sb0, u0.x, fmaf(sb1, u1.x, fmaf(sb2, u2.x, fmaf(sb3, u3.x, axB))));
            ayB = fmaf(sb0, u0.y, fmaf(sb1, u1.y, fmaf(sb2, u2.y, fmaf(sb3, u3.y, ayB))));
            eA += 4; eB += 4;
        }
        for (; eA < EA; eA++) {
            int c = cl[eA]; float s = se[c]; float2 v = LDX(XA, c);
            axA = fmaf(s, v.x, axA); ayA = fmaf(s, v.y, ayA);
        }
        for (; eB < EB; eB++) {
            int c = cl[eB]; float s = se[c]; float2 v = LDX(XA, c);
            axB = fmaf(s, v.x, axB); ayB = fmaf(s, v.y, ayB);
        }
        float sA = scales[N_NODES + rowA], sB = scales[N_NODES + rowB];
        *(__half2*)(agg0 + (size_t)rowA * 128 + 2 * lane) = __floats2half2_rn(axA * sA, ayA * sA);
        *(__half2*)(agg0 + (size_t)rowB * 128 + 2 * lane) = __floats2half2_rn(axB * sB, ayB * sB);
    } else {
        int r = t - 25000;
        const int* rp1 = row_ptr + (N_NODES + 1);
        const int* rp2 = row_ptr + 2 * (N_NODES + 1);
        const unsigned short* cl1 = col + E_EDGES;
        const unsigned short* cl2 = col + 2 * (size_t)E_EDGES;
        const float* se1 = scales + 2 * N_NODES;   // ratedby_src (B)
        const float* se2 = scales + 4 * N_NODES;   // follows_src (A)
        int e1 = rp1[r], E1 = rp1[r + 1];
        int e2 = rp2[r], E2 = rp2[r + 1];
        float a1x = 0.f, a1y = 0.f, a2x = 0.f, a2y = 0.f;
        while (e1 + 4 <= E1 && e2 + 4 <= E2) {
            int a0 = cl1[e1], a1 = cl1[e1+1], a2 = cl1[e1+2], a3 = cl1[e1+3];
            int b0 = cl2[e2], b1 = cl2[e2+1], b2 = cl2[e2+2], b3 = cl2[e2+3];
            float sa0 = se1[a0], sa1 = se1[a1], sa2 = se1[a2], sa3 = se1[a3];
            float sb0 = se2[b0], sb1 = se2[b1], sb2 = se2[b2], sb3 = se2[b3];
            float2 v0 = LDX(XB, a0), v1 = LDX(XB, a1), v2 = LDX(XB, a2), v3 = LDX(XB, a3);
            float2 u0 = LDX(XA, b0), u1 = LDX(XA, b1), u2 = LDX(XA, b2), u3 = LDX(XA, b3);
            a1x = fmaf(sa0, v0.x, fmaf(sa1, v1.x, fmaf(sa2, v2.x, fmaf(sa3, v3.x, a1x))));
            a1y = fmaf(sa0, v0.y, fmaf(sa1, v1.y, fmaf(sa2, v2.y, fmaf(sa3, v3.y, a1y))));
            a2x = fmaf(sb0, u0.x, fmaf(sb1, u1.x, fmaf(sb2, u2.x, fmaf(sb3, u3.x, a2x))));
            a2y = fmaf(sb0, u0.y, fmaf(sb1, u1.y, fmaf(sb2, u2.y, fmaf(sb3, u3.y, a2y))));
            e1 += 4; e2 += 4;
        }
        for (; e1 < E1; e1++) {
            int c = cl1[e1]; float s = se1[c]; float2 v = LDX(XB, c);
            a1x = fmaf(s, v.x, a1x); a1y = fmaf(s, v.y, a1y);
        }
        for (; e2 < E2; e2++) {
            int c = cl2[e2]; float s = se2[c]; float2 v = LDX(XA, c);
            a2x = fmaf(s, v.x, a2x); a2y = fmaf(s, v.y, a2y);
        }
        float s3 = scales[3 * N_NODES + r], s5 = scales[5 * N_NODES + r];
        *(__half2*)(aggA + (size_t)r * 256 + 2 * lane) = __floats2half2_rn(a1x * s3, a1y * s3);
        *(__half2*)(aggA + (size_t)r * 256 + 128 + 2 * lane) = __floats2half2_rn(a2x * s5, a2y * s5);
    }
#undef LDX
}

// --------------------------------------------- MFMA GEMM core
// EPI 0: OUT = diag(sc)*(X@W)            (layer-2 Tp)
// EPI 1: OUT = relu(X@W + bs1)           (hB)
// EPI 2: OUT = relu(X@W + bs1 + bs2)     (hA, K=256 concat)
template <int NCOL, int KD, int EPI>
__device__ __forceinline__ void gemm_core(const __half* __restrict__ X,
                                          const __half* __restrict__ Wt,
                                          __half* __restrict__ OUT,
                                          const float* __restrict__ sc,
                                          const float* __restrict__ bs1,
                                          const float* __restrict__ bs2,
                                          int bxr, int nblocks) {
    constexpr int NHALF = NCOL / 64;
    constexpr int KB = KD / 32;
    int gw = bxr * 4 + ((int)threadIdx.x >> 6);
    int lane = threadIdx.x & 63;
    int half_id = gw % NHALF;
    int mstream = gw / NHALF;
    int nstreams = nblocks * 4 / NHALF;
    int l15 = lane & 15, g = lane >> 4;

    f16x8 b[4][KB];
    float bias_nt[4];
#pragma unroll
    for (int nt = 0; nt < 4; nt++) {
        int colv = half_id * 64 + nt * 16 + l15;
        const __half* wb = Wt + (size_t)colv * KD + g * 8;
#pragma unroll
        for (int kb = 0; kb < KB; kb++)
            b[nt][kb] = *(const f16x8*)(wb + kb * 32);
        if (EPI == 1) bias_nt[nt] = bs1[colv];
        if (EPI == 2) bias_nt[nt] = bs1[colv] + bs2[colv];
    }

    for (int mt = mstream; mt < MTILES; mt += nstreams) {
        int m0 = mt * 16;
        const _Float16* xr = (const _Float16*)X + (size_t)(m0 + l15) * KD + g * 8;
        f16x8 a[KB];
#pragma unroll
        for (int kb = 0; kb < KB; kb++)
            a[kb] = *(const f16x8*)(xr + kb * 32);
        f32x4 acc[4];
#pragma unroll
        for (int nt = 0; nt < 4; nt++) acc[nt] = (f32x4){0.f, 0.f, 0.f, 0.f};
#pragma unroll
        for (int kb = 0; kb < KB; kb++)
#pragma unroll
            for (int nt = 0; nt < 4; nt++)
                acc[nt] = __builtin_amdgcn_mfma_f32_16x16x32_f16(a[kb], b[nt][kb], acc[nt], 0, 0, 0);
        int mrow = m0 + g * 4;
#pragma unroll
        for (int j = 0; j < 4; j++) {
            int row = mrow + j;
            float sj = (EPI == 0) ? sc[row] : 0.f;
            __half* tj = OUT + (size_t)row * NCOL + half_id * 64 + l15;
#pragma unroll
            for (int nt = 0; nt < 4; nt++) {
                float v = acc[nt][j];
                if (EPI == 0) v *= sj;
                else { v += bias_nt[nt]; v = fmaxf(v, 0.f); }
                tj[nt * 16] = __float2half(v);
            }
        }
    }
}

#define GBH 256
#define GBA 384
#define GB2 256

// ---------------- dispatch 6: hB = relu(agg0 @ W1_rates + b1r) ---------------
__global__ __launch_bounds__(256) void gemm_hB(const __half* __restrict__ agg0,
                                               const __half* __restrict__ Wt,
                                               const float* __restrict__ b1r,
                                               __half* __restrict__ hB) {
    gemm_core<128, 128, 1>(agg0, Wt, hB, nullptr, b1r, nullptr, blockIdx.x, GBH);
}

// ---------------- dispatch 7: hA = relu(aggA @ [W1rb;W1f] + b1rb + b1f) ------
__global__ __launch_bounds__(256) void gemm_hA(const __half* __restrict__ aggA,
                                               const __half* __restrict__ Wt,
                                               const float* __restrict__ b1rb,
                                               const float* __restrict__ b1f,
                                               __half* __restrict__ hA) {
    gemm_core<128, 256, 2>(aggA, Wt + 16384, hA, nullptr, b1rb, b1f, blockIdx.x, GBA);
}

// ---------------- dispatch 8: layer-2 GEMMs: Tp = diag(s_out)(h @ W2) --------
__global__ __launch_bounds__(256) void gemm_l2(const __half* __restrict__ hA,
                                               const __half* __restrict__ hB,
                                               const float* __restrict__ scales,
                                               const __half* __restrict__ Wt,
                                               __half* __restrict__ Tp) {
    int rel = blockIdx.x / GB2, bxr = blockIdx.x % GB2;
    const __half* X = (rel == 1) ? hB : hA;
    const float* sc = scales + (rel == 0 ? 0 : rel == 1 ? 2 * N_NODES : 4 * N_NODES);
    gemm_core<64, 128, 0>(X, Wt + 49152 + rel * 8192, Tp + (size_t)rel * N_NODES * 64,
                          sc, nullptr, nullptr, bxr, GB2);
}

// ---------------- dispatch 9: layer-2 SpMM (R7 structure, u16 col) -----------
__global__ __launch_bounds__(256) void spmm_l2(
        const int* __restrict__ row_ptr, const unsigned short* __restrict__ col,
        const __half* __restrict__ Tp, const float* __restrict__ scales,
        const float* __restrict__ b2r, const float* __restrict__ b2rb,
        const float* __restrict__ b2f,
        __half* __restrict__ oB, __half* __restrict__ oA) {
    int g = (blockIdx.x * blockDim.x + threadIdx.x) >> 5;
    int l2 = threadIdx.x & 31;
    unsigned loff = (unsigned)l2 << 2;
    const char* T0 = (const char*)Tp;
    const char* T1 = T0 + (size_t)N_NODES * 128;
    const char* T2 = T1 + (size_t)N_NODES * 128;
#define LDT(B, c) __half22float2(*(const __half2*)((B) + (((unsigned)(c) << 7) + loff)))
    if (g < N_NODES / 2) {
        const unsigned short* cl = col;
        int rowA = g * 2, rowB = rowA + 1;
        int eA = row_ptr[rowA], EA = row_ptr[rowA + 1];
        int eB = EA, EB = row_ptr[rowB + 1];
        float axA = 0.f, ayA = 0.f, axB = 0.f, ayB = 0.f;
        while (eA + 4 <= EA && eB + 4 <= EB) {
            int a0 = cl[eA], a1 = cl[eA+1], a2 = cl[eA+2], a3 = cl[eA+3];
            int b0 = cl[eB], b1 = cl[eB+1], b2 = cl[eB+2], b3 = cl[eB+3];
            float2 v0 = LDT(T0, a0), v1 = LDT(T0, a1), v2 = LDT(T0, a2), v3 = LDT(T0, a3);
            float2 u0 = LDT(T0, b0), u1 = LDT(T0, b1), u2 = LDT(T0, b2), u3 = LDT(T0, b3);
            axA += (v0.x + v1.x) + (v2.x + v3.x); ayA += (v0.y + v1.y) + (v2.y + v3.y);
            axB += (u0.x + u1.x) + (u2.x + u3.x); ayB += (u0.y + u1.y) + (u2.y + u3.y);
            eA += 4; eB += 4;
        }
        for (; eA < EA; eA++) { float2 v = LDT(T0, cl[eA]); axA += v.x; ayA += v.y; }
        for (; eB < EB; eB++) { float2 v = LDT(T0, cl[eB]); axB += v.x; ayB += v.y; }
        float bx = b2r[2 * l2], by = b2r[2 * l2 + 1];
        float sA = scales[N_NODES + rowA], sB = scales[N_NODES + rowB];
        *(__half2*)(oB + (size_t)rowA * 64 + 2 * l2) =
            __floats2half2_rn(fmaf(axA, sA, bx), fmaf(ayA, sA, by));
        *(__half2*)(oB + (size_t)rowB * 64 + 2 * l2) =
            __floats2half2_rn(fmaf(axB, sB, bx), fmaf(ayB, sB, by));
    } else {
        int r = g - N_NODES / 2;
        const int* rp1 = row_ptr + (N_NODES + 1);
        const int* rp2 = row_ptr + 2 * (N_NODES + 1);
        const unsigned short* cl1 = col + E_EDGES;
        const unsigned short* cl2 = col + 2 * (size_t)E_EDGES;
        int e1 = rp1[r], E1 = rp1[r + 1];
        int e2 = rp2[r], E2 = rp2[r + 1];
        float a1x = 0.f, a1y = 0.f, a2x = 0.f, a2y = 0.f;
        while (e1 + 4 <= E1 && e2 + 4 <= E2) {
            int a0 = cl1[e1], a1 = cl1[e1+1], a2 = cl1[e1+2], a3 = cl1[e1+3];
            int b0 = cl2[e2], b1 = cl2[e2+1], b2 = cl2[e2+2], b3 = cl2[e2+3];
            float2 v0 = LDT(T1, a0), v1 = LDT(T1, a1), v2 = LDT(T1, a2), v3 = LDT(T1, a3);
            float2 u0 = LDT(T2, b0), u1 = LDT(T2, b1), u2 = LDT(T2, b2), u3 = LDT(T2, b3);
            a1x += (v0.x + v1.x) + (v2.x + v3.x); a1y += (v0.y + v1.y) + (v2.y + v3.y);
            a2x += (u0.x + u1.x) + (u2.x + u3.x); a2y += (u0.y + u1.y) + (u2.y + u3.y);
            e1 += 4; e2 += 4;
        }
        for (; e1 < E1; e1++) { float2 v = LDT(T1, cl1[e1]); a1x += v.x; a1y += v.y; }
        for (; e2 < E2; e2++) { float2 v = LDT(T2, cl2[e2]); a2x += v.x; a2y += v.y; }
        float s1 = scales[3 * N_NODES + r], s2 = scales[5 * N_NODES + r];
        float ox = a1x * s1 + a2x * s2 + b2rb[2 * l2] + b2f[2 * l2];
        float oy = a1y * s1 + a2y * s2 + b2rb[2 * l2 + 1] + b2f[2 * l2 + 1];
        *(__half2*)(oA + (size_t)r * 64 + 2 * l2) = __floats2half2_rn(ox, oy);
    }
#undef LDT
}

// ---------------- dispatch 10: scoring (pos + neg fused) ---------------------
__global__ __launch_bounds__(256) void score2(const __half* __restrict__ oA,
                                              const __half* __restrict__ oB,
                                              const int* __restrict__ ps,
                                              const int* __restrict__ pd,
                                              const int* __restrict__ ns,
                                              const int* __restrict__ nd,
                                              float* __restrict__ out) {
    int g = (blockIdx.x * blockDim.x + threadIdx.x) >> 4;
    int l = threadIdx.x & 15;
    int ng = (gridDim.x * blockDim.x) >> 4;
    const char* A = (const char*)oA;
    const char* B = (const char*)oB;
    unsigned loff = (unsigned)l << 3;
#define SCORE_LOOP(SRC, DST, OUT)                                               \
    for (int e0 = g * 2; e0 < E_EDGES; e0 += ng * 2) {                          \
        int e1 = e0 + 1;                                                        \
        int s0 = SRC[e0], d0 = DST[e0], s1 = SRC[e1], d1 = DST[e1];             \
        union { uint2 u; __half2 h[2]; } a0, b0, a1, b1;                        \
        a0.u = *(const uint2*)(A + (((unsigned)s0 << 7) + loff));               \
        b0.u = *(const uint2*)(B + (((unsigned)d0 << 7) + loff));               \
        a1.u = *(const uint2*)(A + (((unsigned)s1 << 7) + loff));               \
        b1.u = *(const uint2*)(B + (((unsigned)d1 << 7) + loff));               \
        float2 fa, fb;                                                          \
        fa = __half22float2(a0.h[0]); fb = __half22float2(b0.h[0]);             \
        float p0 = fa.x * fb.x + fa.y * fb.y;                                   \
        fa = __half22float2(a0.h[1]); fb = __half22float2(b0.h[1]);             \
        p0 += fa.x * fb.x + fa.y * fb.y;                                        \
        fa = __half22float2(a1.h[0]); fb = __half22float2(b1.h[0]);             \
        float p1 = fa.x * fb.x + fa.y * fb.y;                                   \
        fa = __half22float2(a1.h[1]); fb = __half22float2(b1.h[1]);             \
        p1 += fa.x * fb.x + fa.y * fb.y;                                        \
        p0 += __shfl_xor(p0, 8); p1 += __shfl_xor(p1, 8);                       \
        p0 += __shfl_xor(p0, 4); p1 += __shfl_xor(p1, 4);                       \
        p0 += __shfl_xor(p0, 2); p1 += __shfl_xor(p1, 2);                       \
        p0 += __shfl_xor(p0, 1); p1 += __shfl_xor(p1, 1);                       \
        if (l == 0) { OUT[e0] = p0; OUT[e1] = p1; }                             \
    }
    SCORE_LOOP(ps, pd, out)
    float* outn = out + E_EDGES;
    SCORE_LOOP(ns, nd, outn)
#undef SCORE_LOOP
}

// ---------------------------------------------------------------------------
extern "C" void kernel_launch(void* const* d_in, const int* in_sizes, int n_in,
                              void* d_out, int out_size, void* d_ws, size_t ws_size,
                              hipStream_t stream) {
    const float* feat_A     = (const float*)d_in[0];
    const float* feat_B     = (const float*)d_in[1];
    const int* rates_src    = (const int*)d_in[2];
    const int* rates_dst    = (const int*)d_in[3];
    const int* ratedby_src  = (const int*)d_in[4];
    const int* ratedby_dst  = (const int*)d_in[5];
    const int* follows_src  = (const int*)d_in[6];
    const int* follows_dst  = (const int*)d_in[7];
    const int* neg_src      = (const int*)d_in[8];
    const int* neg_dst      = (const int*)d_in[9];
    const float* W1_rates   = (const float*)d_in[10];
    const float* b1_rates   = (const float*)d_in[11];
    const float* W1_ratedby = (const float*)d_in[12];
    const float* b1_ratedby = (const float*)d_in[13];
    const float* W1_follows = (const float*)d_in[14];
    const float* b1_follows = (const float*)d_in[15];
    const float* W2_rates   = (const float*)d_in[16];
    const float* b2_rates   = (const float*)d_in[17];
    const float* W2_ratedby = (const float*)d_in[18];
    const float* b2_ratedby = (const float*)d_in[19];
    const float* W2_follows = (const float*)d_in[20];
    const float* b2_follows = (const float*)d_in[21];

    const int N = N_NODES, E = E_EDGES;

    char* ws = (char*)d_ws;
    size_t off = 0;
    auto alloc = [&](size_t bytes) -> void* {
        void* p = ws + off;
        off += (bytes + 255) & ~(size_t)255;
        return p;
    };
    float* scales = (float*)alloc((size_t)6 * N * 4);
    int* row_ptr  = (int*)alloc((size_t)3 * (N + 1) * 4);
    int* bphist   = (int*)alloc((size_t)6 * HB * NBUCK * 4);
    int* gbase    = (int*)alloc((size_t)6 * (NBUCK + 1) * 4);
    int* gcur     = (int*)alloc((size_t)6 * NBUCK * 4);
    unsigned short* col = (unsigned short*)alloc((size_t)3 * E * 2);
    // region1: pairs(12MB)+sbytes(3MB); agg0(12.8MB) aliases it (pairs/sbytes
    // dead after fused_finish; agg0 written by spmm_l1).
    char* region1 = (char*)alloc((size_t)16 * 1024 * 1024);
    unsigned* pairs = (unsigned*)region1;
    unsigned char* sbytes = (unsigned char*)(pairs + (size_t)3 * E);
    __half* agg0 = (__half*)region1;
    // regionX: X_Ah(12.8MB); oA/oB alias it (X_Ah dead after spmm_l1).
    char* regionX = (char*)alloc((size_t)N * 128 * 2);
    __half* XAh = (__half*)regionX;
    __half* oA  = (__half*)regionX;
    __half* oB  = oA + (size_t)N * 64;
    // regionA: aggA(25.6MB); Tp(19.2MB) aliases it (aggA dead after gemm_hA).
    char* regionA = (char*)alloc((size_t)N * 256 * 2);
    __half* aggA = (__half*)regionA;
    __half* Tp   = (__half*)regionA;
    __half* XBh  = (__half*)alloc((size_t)N * 128 * 2);
    __half* hA   = (__half*)alloc((size_t)N * 128 * 2);
    __half* hB   = (__half*)alloc((size_t)N * 128 * 2);
    __half* Wt   = (__half*)alloc((size_t)73728 * 2);
    (void)ws_size;

    fused0<<<6 * HB + 96 + 256, 256, 0, stream>>>(
        W1_rates, W1_ratedby, W1_follows, W2_rates, W2_ratedby, W2_follows, Wt,
        feat_A, feat_B, XAh, XBh,
        rates_src, rates_dst, ratedby_src, ratedby_dst, follows_src, follows_dst,
        bphist);
    bucket_scan_par<<<6, 256, 0, stream>>>(bphist, gbase, gcur);
    fused_bin<<<dim3(256, 6), 256, 0, stream>>>(rates_src, rates_dst, ratedby_src,
                                                ratedby_dst, follows_src, follows_dst,
                                                gcur, pairs, sbytes);
    fused_finish<<<dim3(NBUCK, 6), 256, 0, stream>>>(pairs, sbytes, gbase,
                                                     row_ptr, scales, col);

    spmm_l1<<<(3 * N / 2) / 4, 256, 0, stream>>>(row_ptr, col, XAh, XBh, scales,
                                                 agg0, aggA);
    gemm_hB<<<GBH, 256, 0, stream>>>(agg0, Wt, b1_rates, hB);
    gemm_hA<<<GBA, 256, 0, stream>>>(aggA, Wt, b1_ratedby, b1_follows, hA);
    gemm_l2<<<3 * GB2, 256, 0, stream>>>(hA, hB, scales, Wt, Tp);
    spmm_l2<<<(3 * N / 2) / 8, 256, 0, stream>>>(row_ptr, col, Tp, scales,
                                                 b2_rates, b2_ratedby, b2_follows,
                                                 oB, oA);
    score2<<<8192, 256, 0, stream>>>(oA, oB, rates_src, rates_dst,
                                     neg_src, neg_dst, (float*)d_out);
}

// Round 12
// 356.659 us; speedup vs baseline: 1.8232x; 1.1278x over previous
//
#include <hip/hip_runtime.h>
#include <hip/hip_fp16.h>
#include <cstddef>
#include <type_traits>

#define N_NODES 50000
#define E_EDGES 1000000
#define NBUCK 196
#define ACHUNK 3907
#define MTILES 3125
#define HB 96
#define HCHUNK 10417
#define GB1 384
#define GB2 256

typedef _Float16 f16x8 __attribute__((ext_vector_type(8)));
typedef float f32x4 __attribute__((ext_vector_type(4)));

// ---------------- dispatch 1: hist partials || weight cvt --------------------
__global__ __launch_bounds__(256) void fused0(
        const float* __restrict__ w0, const float* __restrict__ w1,
        const float* __restrict__ w2, const float* __restrict__ w3,
        const float* __restrict__ w4, const float* __restrict__ w5,
        __half* __restrict__ Wt,
        const int* __restrict__ rs, const int* __restrict__ rd,
        const int* __restrict__ bs, const int* __restrict__ bd,
        const int* __restrict__ fs, const int* __restrict__ fd,
        int* __restrict__ bphist) {
    int bx = blockIdx.x;
    if (bx < 6 * HB) {
        __shared__ int l[NBUCK];
        int arr = bx / HB, blk = bx % HB;
        const int* idx = arr == 0 ? rs : arr == 1 ? rd : arr == 2 ? bs
                       : arr == 3 ? bd : arr == 4 ? fs : fd;
        for (int b = threadIdx.x; b < NBUCK; b += 256) l[b] = 0;
        __syncthreads();
        int e0 = blk * HCHUNK;
        int e1 = e0 + HCHUNK; if (e1 > E_EDGES) e1 = E_EDGES;
        for (int i = e0 + threadIdx.x; i < e1; i += 256)
            atomicAdd(&l[((unsigned)idx[i]) >> 8], 1);
        __syncthreads();
        int* dst = bphist + (size_t)(arr * HB + blk) * NBUCK;
        for (int b = threadIdx.x; b < NBUCK; b += 256) dst[b] = l[b];
        return;
    }
    bx -= 6 * HB;
    int m = bx / 16, part = bx % 16;
    const float* W = m == 0 ? w0 : m == 1 ? w1 : m == 2 ? w2 : m == 3 ? w3 : m == 4 ? w4 : w5;
    __half* Tt = Wt + (m < 3 ? m * 16384 : 49152 + (m - 3) * 8192);
    int ncol = m < 3 ? 128 : 64;
    int tot = 128 * ncol;
    for (int i = part * 256 + threadIdx.x; i < tot; i += 16 * 256) {
        int n = i >> 7, k = i & 127;          // Wt[n][k] = W[k][n]
        Tt[i] = __float2half(W[k * ncol + n]);
    }
}

// ---------------- dispatch 2: parallel bucket scan -> gbase, gcur ------------
__global__ void bucket_scan_par(const int* __restrict__ bphist, int* __restrict__ gbase,
                                int* __restrict__ gcur) {
    int arr = blockIdx.x;
    int t = threadIdx.x;
    int c = 0;
    if (t < NBUCK) {
        const int* p = bphist + (size_t)arr * HB * NBUCK + t;
#pragma unroll 8
        for (int blk = 0; blk < HB; blk++) c += p[(size_t)blk * NBUCK];
    }
    int lane = t & 63, wid = t >> 6;
    __shared__ int wsum[4];
    int v = c;
#pragma unroll
    for (int o = 1; o < 64; o <<= 1) { int u = __shfl_up(v, o); if (lane >= o) v += u; }
    if (lane == 63) wsum[wid] = v;
    __syncthreads();
    int base = 0;
    for (int ww = 0; ww < wid; ww++) base += wsum[ww];
    int excl = base + v - c;
    if (t < NBUCK) {
        gbase[arr * (NBUCK + 1) + t] = excl;
        gcur[arr * NBUCK + t] = excl;
    }
    if (t == 255) gbase[arr * (NBUCK + 1) + NBUCK] = base + v;
}

// ---------------- dispatch 3: binP (y<3) || binS (y>=3) ----------------------
__global__ __launch_bounds__(256) void fused_bin(
        const int* __restrict__ rs, const int* __restrict__ rd,
        const int* __restrict__ bs, const int* __restrict__ bd,
        const int* __restrict__ fs, const int* __restrict__ fd,
        int* __restrict__ gcur, unsigned* __restrict__ pairs,
        unsigned char* __restrict__ sbytes) {
    int y = blockIdx.y;
    __shared__ int lcnt[NBUCK];
    __shared__ int lbase[NBUCK];
    int e0 = blockIdx.x * ACHUNK;
    int e1 = e0 + ACHUNK; if (e1 > E_EDGES) e1 = E_EDGES;
    for (int b = threadIdx.x; b < NBUCK; b += 256) lcnt[b] = 0;
    __syncthreads();
    if (y < 3) {
        int rel = y, arr = 2 * rel + 1;
        const int* src = rel == 0 ? rs : rel == 1 ? bs : fs;
        const int* dst = rel == 0 ? rd : rel == 1 ? bd : fd;
        for (int i = e0 + threadIdx.x; i < e1; i += 256)
            atomicAdd(&lcnt[((unsigned)dst[i]) >> 8], 1);
        __syncthreads();
        for (int b = threadIdx.x; b < NBUCK; b += 256) {
            lbase[b] = lcnt[b] ? atomicAdd(&gcur[arr * NBUCK + b], lcnt[b]) : 0;
            lcnt[b] = 0;
        }
        __syncthreads();
        unsigned* pp = pairs + (size_t)rel * E_EDGES;
        for (int i = e0 + threadIdx.x; i < e1; i += 256) {
            int d = dst[i];
            int b = ((unsigned)d) >> 8;
            int p = lbase[b] + atomicAdd(&lcnt[b], 1);
            pp[p] = ((unsigned)(d & 255) << 16) | (unsigned)src[i];
        }
    } else {
        int rel = y - 3, arr = 2 * rel;
        const int* src = rel == 0 ? rs : rel == 1 ? bs : fs;
        for (int i = e0 + threadIdx.x; i < e1; i += 256)
            atomicAdd(&lcnt[((unsigned)src[i]) >> 8], 1);
        __syncthreads();
        for (int b = threadIdx.x; b < NBUCK; b += 256) {
            lbase[b] = lcnt[b] ? atomicAdd(&gcur[arr * NBUCK + b], lcnt[b]) : 0;
            lcnt[b] = 0;
        }
        __syncthreads();
        unsigned char* sb = sbytes + (size_t)rel * E_EDGES;
        for (int i = e0 + threadIdx.x; i < e1; i += 256) {
            int s = src[i];
            int b = ((unsigned)s) >> 8;
            int p = lbase[b] + atomicAdd(&lcnt[b], 1);
            sb[p] = (unsigned char)(s & 255);
        }
    }
}

// ---------------- dispatch 4: countS (y<3) || fillB2 (y>=3), u16 col ---------
__global__ __launch_bounds__(256) void fused_finish(
        const unsigned* __restrict__ pairs, const unsigned char* __restrict__ sbytes,
        const int* __restrict__ gbase, int* __restrict__ row_ptr,
        float* __restrict__ scales, unsigned short* __restrict__ col) {
    int y = blockIdx.y, b = blockIdx.x, t = threadIdx.x;
    __shared__ int cnt[256];
    __shared__ int rowbase[256];
    __shared__ int wsum[4];
    if (y < 3) {
        int rel = y, arr = 2 * rel;
        int p0 = gbase[arr * (NBUCK + 1) + b];
        int p1 = gbase[arr * (NBUCK + 1) + b + 1];
        const unsigned char* sb = sbytes + (size_t)rel * E_EDGES;
        cnt[t] = 0;
        __syncthreads();
        for (int i = p0 + t; i < p1; i += 256)
            atomicAdd(&cnt[sb[i]], 1);
        __syncthreads();
        int node = b * 256 + t;
        if (node < N_NODES) {
            int c = cnt[t]; if (c < 1) c = 1;
            scales[(size_t)arr * N_NODES + node] = 1.0f / sqrtf((float)c);
        }
    } else {
        int rel = y - 3, arr = 2 * rel + 1;
        int gb = gbase[arr * (NBUCK + 1) + b];
        int ge = gbase[arr * (NBUCK + 1) + b + 1];
        const unsigned* pp = pairs + (size_t)rel * E_EDGES;
        cnt[t] = 0;
        __syncthreads();
        for (int i = gb + t; i < ge; i += 256)
            atomicAdd(&cnt[pp[i] >> 16], 1);
        __syncthreads();
        int lane = t & 63, wid = t >> 6;
        int c0 = cnt[t];
        int v = c0;
#pragma unroll
        for (int o = 1; o < 64; o <<= 1) { int u = __shfl_up(v, o); if (lane >= o) v += u; }
        if (lane == 63) wsum[wid] = v;
        __syncthreads();
        int base = gb;
        for (int w = 0; w < wid; w++) base += wsum[w];
        int excl = base + v - c0;
        rowbase[t] = excl;
        int node = b * 256 + t;
        if (node <= N_NODES)
            row_ptr[(size_t)rel * (N_NODES + 1) + node] = excl;
        if (node < N_NODES) {
            int c = c0; if (c < 1) c = 1;
            scales[(size_t)arr * N_NODES + node] = 1.0f / sqrtf((float)c);
        }
        cnt[t] = 0;
        __syncthreads();
        unsigned short* cl = col + (size_t)rel * E_EDGES;
        for (int i = gb + t; i < ge; i += 256) {
            unsigned p = pp[i];
            int dl = p >> 16;
            int slot = rowbase[dl] + atomicAdd(&cnt[dl], 1);
            cl[slot] = (unsigned short)(p & 0xFFFFu);
        }
    }
}

// --------------------------------------------- MFMA GEMM body: T = diag(s)*(X@W)
template <int NCOL, typename XT>
__device__ __forceinline__ void gemm_body(const XT* __restrict__ X,
                                          const float* __restrict__ sc,
                                          const __half* __restrict__ Wt,
                                          __half* __restrict__ T,
                                          int bxr, int nblocks) {
    constexpr int NHALF = NCOL / 64;
    int gw = bxr * 4 + ((int)threadIdx.x >> 6);
    int lane = threadIdx.x & 63;
    int half_id = gw % NHALF;
    int mstream = gw / NHALF;
    int nstreams = nblocks * 4 / NHALF;
    int l15 = lane & 15, g = lane >> 4;

    f16x8 b[4][4];
    {
        const __half* wb = Wt + ((size_t)half_id * 64 + l15) * 128 + g * 8;
#pragma unroll
        for (int nt = 0; nt < 4; nt++)
#pragma unroll
            for (int kb = 0; kb < 4; kb++)
                b[nt][kb] = *(const f16x8*)(wb + nt * 16 * 128 + kb * 32);
    }

    for (int mt = mstream; mt < MTILES; mt += nstreams) {
        int m0 = mt * 16;
        f16x8 a[4];
        if constexpr (std::is_same<XT, float>::value) {
            const float* xr = X + (size_t)(m0 + l15) * 128 + g * 8;
#pragma unroll
            for (int kb = 0; kb < 4; kb++) {
                float4 u = *(const float4*)(xr + kb * 32);
                float4 v = *(const float4*)(xr + kb * 32 + 4);
                f16x8 t;
                t[0] = (_Float16)u.x; t[1] = (_Float16)u.y;
                t[2] = (_Float16)u.z; t[3] = (_Float16)u.w;
                t[4] = (_Float16)v.x; t[5] = (_Float16)v.y;
                t[6] = (_Float16)v.z; t[7] = (_Float16)v.w;
                a[kb] = t;
            }
        } else {
            const _Float16* xr = (const _Float16*)X + (size_t)(m0 + l15) * 128 + g * 8;
#pragma unroll
            for (int kb = 0; kb < 4; kb++)
                a[kb] = *(const f16x8*)(xr + kb * 32);
        }
        f32x4 acc[4];
#pragma unroll
        for (int nt = 0; nt < 4; nt++) acc[nt] = (f32x4){0.f, 0.f, 0.f, 0.f};
#pragma unroll
        for (int kb = 0; kb < 4; kb++)
#pragma unroll
            for (int nt = 0; nt < 4; nt++)
                acc[nt] = __builtin_amdgcn_mfma_f32_16x16x32_f16(a[kb], b[nt][kb], acc[nt], 0, 0, 0);
        int mrow = m0 + g * 4;
#pragma unroll
        for (int j = 0; j < 4; j++) {
            float sj = sc[mrow + j];
            __half* tj = T + (size_t)(mrow + j) * NCOL + half_id * 64 + l15;
            tj[0]  = __float2half(acc[0][j] * sj);
            tj[16] = __float2half(acc[1][j] * sj);
            tj[32] = __float2half(acc[2][j] * sj);
            tj[48] = __float2half(acc[3][j] * sj);
        }
    }
}

// ---------------- dispatch 5: layer-1 GEMMs (3 relations) --------------------
__global__ __launch_bounds__(256) void gemm_l1(const float* __restrict__ fA,
                                               const float* __restrict__ fB,
                                               const float* __restrict__ scales,
                                               const __half* __restrict__ Wt,
                                               __half* __restrict__ T012) {
    int rel = blockIdx.x / GB1, bxr = blockIdx.x % GB1;
    const float* X = (rel == 1) ? fB : fA;
    const float* sc = scales + (rel == 0 ? 0 : rel == 1 ? 2 * N_NODES : 4 * N_NODES);
    const __half* W = Wt + rel * 16384;
    __half* T = T012 + (size_t)rel * N_NODES * 128;
    gemm_body<128, float>(X, sc, W, T, bxr, GB1);
}

// ---------------- dispatch 7: layer-2 GEMMs (3 relations) --------------------
__global__ __launch_bounds__(256) void gemm_l2(const __half* __restrict__ hA,
                                               const __half* __restrict__ hB,
                                               const float* __restrict__ scales,
                                               const __half* __restrict__ Wt,
                                               __half* __restrict__ Tp) {
    int rel = blockIdx.x / GB2, bxr = blockIdx.x % GB2;
    const __half* X = (rel == 1) ? hB : hA;
    const float* sc = scales + (rel == 0 ? 0 : rel == 1 ? 2 * N_NODES : 4 * N_NODES);
    const __half* W = Wt + 49152 + rel * 8192;
    __half* T = Tp + (size_t)rel * N_NODES * 64;
    gemm_body<64, __half>(X, sc, W, T, bxr, GB2);
}

// ---------------- dispatch 6: layer-1 fused SpMM (R7 structure, u16 col) -----
__global__ __launch_bounds__(256) void spmm_l1(
        const int* __restrict__ row_ptr, const unsigned short* __restrict__ col,
        const __half* __restrict__ T012, const float* __restrict__ scales,
        const float* __restrict__ b1r, const float* __restrict__ b1rb,
        const float* __restrict__ b1f,
        __half* __restrict__ hB, __half* __restrict__ hA) {
    int w = (blockIdx.x * blockDim.x + threadIdx.x) >> 6;
    int lane = threadIdx.x & 63;
    unsigned loff = (unsigned)lane << 2;
    const char* T0 = (const char*)T012;
    const char* T1 = T0 + (size_t)N_NODES * 256;
    const char* T2 = T1 + (size_t)N_NODES * 256;
#define LDT(B, c) __half22float2(*(const __half2*)((B) + (((unsigned)(c) << 8) + loff)))
    if (w < N_NODES / 2) {
        const unsigned short* cl = col;
        int rowA = w * 2, rowB = rowA + 1;
        int eA = row_ptr[rowA], EA = row_ptr[rowA + 1];
        int eB = EA, EB = row_ptr[rowB + 1];
        float axA = 0.f, ayA = 0.f, axB = 0.f, ayB = 0.f;
        while (eA + 4 <= EA && eB + 4 <= EB) {
            int a0 = cl[eA], a1 = cl[eA+1], a2 = cl[eA+2], a3 = cl[eA+3];
            int b0 = cl[eB], b1 = cl[eB+1], b2 = cl[eB+2], b3 = cl[eB+3];
            float2 v0 = LDT(T0, a0), v1 = LDT(T0, a1), v2 = LDT(T0, a2), v3 = LDT(T0, a3);
            float2 u0 = LDT(T0, b0), u1 = LDT(T0, b1), u2 = LDT(T0, b2), u3 = LDT(T0, b3);
            axA += (v0.x + v1.x) + (v2.x + v3.x); ayA += (v0.y + v1.y) + (v2.y + v3.y);
            axB += (u0.x + u1.x) + (u2.x + u3.x); ayB += (u0.y + u1.y) + (u2.y + u3.y);
            eA += 4; eB += 4;
        }
        while (eA + 4 <= EA) {
            int a0 = cl[eA], a1 = cl[eA+1], a2 = cl[eA+2], a3 = cl[eA+3];
            float2 v0 = LDT(T0, a0), v1 = LDT(T0, a1), v2 = LDT(T0, a2), v3 = LDT(T0, a3);
            axA += (v0.x + v1.x) + (v2.x + v3.x); ayA += (v0.y + v1.y) + (v2.y + v3.y);
            eA += 4;
        }
        while (eB + 4 <= EB) {
            int b0 = cl[eB], b1 = cl[eB+1], b2 = cl[eB+2], b3 = cl[eB+3];
            float2 u0 = LDT(T0, b0), u1 = LDT(T0, b1), u2 = LDT(T0, b2), u3 = LDT(T0, b3);
            axB += (u0.x + u1.x) + (u2.x + u3.x); ayB += (u0.y + u1.y) + (u2.y + u3.y);
            eB += 4;
        }
        while (eA < EA && eB < EB) {
            float2 v = LDT(T0, cl[eA]), u = LDT(T0, cl[eB]);
            axA += v.x; ayA += v.y; axB += u.x; ayB += u.y;
            eA++; eB++;
        }
        for (; eA < EA; eA++) { float2 v = LDT(T0, cl[eA]); axA += v.x; ayA += v.y; }
        for (; eB < EB; eB++) { float2 v = LDT(T0, cl[eB]); axB += v.x; ayB += v.y; }
        float bx = b1r[2 * lane], by = b1r[2 * lane + 1];
        float sA = scales[N_NODES + rowA], sB = scales[N_NODES + rowB];
        float ox = fmaxf(fmaf(axA, sA, bx), 0.f), oy = fmaxf(fmaf(ayA, sA, by), 0.f);
        *(__half2*)(hB + (size_t)rowA * 128 + 2 * lane) = __floats2half2_rn(ox, oy);
        ox = fmaxf(fmaf(axB, sB, bx), 0.f); oy = fmaxf(fmaf(ayB, sB, by), 0.f);
        *(__half2*)(hB + (size_t)rowB * 128 + 2 * lane) = __floats2half2_rn(ox, oy);
    } else {
        int r = w - N_NODES / 2;
        const int* rp1 = row_ptr + (N_NODES + 1);
        const int* rp2 = row_ptr + 2 * (N_NODES + 1);
        const unsigned short* cl1 = col + E_EDGES;
        const unsigned short* cl2 = col + 2 * (size_t)E_EDGES;
        int e1 = rp1[r], E1 = rp1[r + 1];
        int e2 = rp2[r], E2 = rp2[r + 1];
        float a1x = 0.f, a1y = 0.f, a2x = 0.f, a2y = 0.f;
        while (e1 + 4 <= E1 && e2 + 4 <= E2) {
            int a0 = cl1[e1], a1 = cl1[e1+1], a2 = cl1[e1+2], a3 = cl1[e1+3];
            int b0 = cl2[e2], b1 = cl2[e2+1], b2 = cl2[e2+2], b3 = cl2[e2+3];
            float2 v0 = LDT(T1, a0), v1 = LDT(T1, a1), v2 = LDT(T1, a2), v3 = LDT(T1, a3);
            float2 u0 = LDT(T2, b0), u1 = LDT(T2, b1), u2 = LDT(T2, b2), u3 = LDT(T2, b3);
            a1x += (v0.x + v1.x) + (v2.x + v3.x); a1y += (v0.y + v1.y) + (v2.y + v3.y);
            a2x += (u0.x + u1.x) + (u2.x + u3.x); a2y += (u0.y + u1.y) + (u2.y + u3.y);
            e1 += 4; e2 += 4;
        }
        while (e1 + 4 <= E1) {
            int a0 = cl1[e1], a1 = cl1[e1+1], a2 = cl1[e1+2], a3 = cl1[e1+3];
            float2 v0 = LDT(T1, a0), v1 = LDT(T1, a1), v2 = LDT(T1, a2), v3 = LDT(T1, a3);
            a1x += (v0.x + v1.x) + (v2.x + v3.x); a1y += (v0.y + v1.y) + (v2.y + v3.y);
            e1 += 4;
        }
        while (e2 + 4 <= E2) {
            int b0 = cl2[e2], b1 = cl2[e2+1], b2 = cl2[e2+2], b3 = cl2[e2+3];
            float2 u0 = LDT(T2, b0), u1 = LDT(T2, b1), u2 = LDT(T2, b2), u3 = LDT(T2, b3);
            a2x += (u0.x + u1.x) + (u2.x + u3.x); a2y += (u0.y + u1.y) + (u2.y + u3.y);
            e2 += 4;
        }
        while (e1 < E1 && e2 < E2) {
            float2 v = LDT(T1, cl1[e1]), u = LDT(T2, cl2[e2]);
            a1x += v.x; a1y += v.y; a2x += u.x; a2y += u.y;
            e1++; e2++;
        }
        for (; e1 < E1; e1++) { float2 v = LDT(T1, cl1[e1]); a1x += v.x; a1y += v.y; }
        for (; e2 < E2; e2++) { float2 v = LDT(T2, cl2[e2]); a2x += v.x; a2y += v.y; }
        float s1 = scales[3 * N_NODES + r], s2 = scales[5 * N_NODES + r];
        float ox = a1x * s1 + a2x * s2 + b1rb[2 * lane] + b1f[2 * lane];
        float oy = a1y * s1 + a2y * s2 + b1rb[2 * lane + 1] + b1f[2 * lane + 1];
        ox = fmaxf(ox, 0.f); oy = fmaxf(oy, 0.f);
        *(__half2*)(hA + (size_t)r * 128 + 2 * lane) = __floats2half2_rn(ox, oy);
    }
#undef LDT
}

// ---------------- dispatch 8: layer-2 fused SpMM (32-lane, u16 col) ----------
__global__ __launch_bounds__(256) void spmm_l2(
        const int* __restrict__ row_ptr, const unsigned short* __restrict__ col,
        const __half* __restrict__ Tp, const float* __restrict__ scales,
        const float* __restrict__ b2r, const float* __restrict__ b2rb,
        const float* __restrict__ b2f,
        __half* __restrict__ oB, __half* __restrict__ oA) {
    int g = (blockIdx.x * blockDim.x + threadIdx.x) >> 5;
    int l2 = threadIdx.x & 31;
    unsigned loff = (unsigned)l2 << 2;
    const char* T0 = (const char*)Tp;
    const char* T1 = T0 + (size_t)N_NODES * 128;
    const char* T2 = T1 + (size_t)N_NODES * 128;
#define LDT(B, c) __half22float2(*(const __half2*)((B) + (((unsigned)(c) << 7) + loff)))
    if (g < N_NODES / 2) {
        const unsigned short* cl = col;
        int rowA = g * 2, rowB = rowA + 1;
        int eA = row_ptr[rowA], EA = row_ptr[rowA + 1];
        int eB = EA, EB = row_ptr[rowB + 1];
        float axA = 0.f, ayA = 0.f, axB = 0.f, ayB = 0.f;
        while (eA + 4 <= EA && eB + 4 <= EB) {
            int a0 = cl[eA], a1 = cl[eA+1], a2 = cl[eA+2], a3 = cl[eA+3];
            int b0 = cl[eB], b1 = cl[eB+1], b2 = cl[eB+2], b3 = cl[eB+3];
            float2 v0 = LDT(T0, a0), v1 = LDT(T0, a1), v2 = LDT(T0, a2), v3 = LDT(T0, a3);
            float2 u0 = LDT(T0, b0), u1 = LDT(T0, b1), u2 = LDT(T0, b2), u3 = LDT(T0, b3);
            axA += (v0.x + v1.x) + (v2.x + v3.x); ayA += (v0.y + v1.y) + (v2.y + v3.y);
            axB += (u0.x + u1.x) + (u2.x + u3.x); ayB += (u0.y + u1.y) + (u2.y + u3.y);
            eA += 4; eB += 4;
        }
        while (eA + 4 <= EA) {
            int a0 = cl[eA], a1 = cl[eA+1], a2 = cl[eA+2], a3 = cl[eA+3];
            float2 v0 = LDT(T0, a0), v1 = LDT(T0, a1), v2 = LDT(T0, a2), v3 = LDT(T0, a3);
            axA += (v0.x + v1.x) + (v2.x + v3.x); ayA += (v0.y + v1.y) + (v2.y + v3.y);
            eA += 4;
        }
        while (eB + 4 <= EB) {
            int b0 = cl[eB], b1 = cl[eB+1], b2 = cl[eB+2], b3 = cl[eB+3];
            float2 u0 = LDT(T0, b0), u1 = LDT(T0, b1), u2 = LDT(T0, b2), u3 = LDT(T0, b3);
            axB += (u0.x + u1.x) + (u2.x + u3.x); ayB += (u0.y + u1.y) + (u2.y + u3.y);
            eB += 4;
        }
        while (eA < EA && eB < EB) {
            float2 v = LDT(T0, cl[eA]), u = LDT(T0, cl[eB]);
            axA += v.x; ayA += v.y; axB += u.x; ayB += u.y;
            eA++; eB++;
        }
        for (; eA < EA; eA++) { float2 v = LDT(T0, cl[eA]); axA += v.x; ayA += v.y; }
        for (; eB < EB; eB++) { float2 v = LDT(T0, cl[eB]); axB += v.x; ayB += v.y; }
        float bx = b2r[2 * l2], by = b2r[2 * l2 + 1];
        float sA = scales[N_NODES + rowA], sB = scales[N_NODES + rowB];
        *(__half2*)(oB + (size_t)rowA * 64 + 2 * l2) =
            __floats2half2_rn(fmaf(axA, sA, bx), fmaf(ayA, sA, by));
        *(__half2*)(oB + (size_t)rowB * 64 + 2 * l2) =
            __floats2half2_rn(fmaf(axB, sB, bx), fmaf(ayB, sB, by));
    } else {
        int r = g - N_NODES / 2;
        const int* rp1 = row_ptr + (N_NODES + 1);
        const int* rp2 = row_ptr + 2 * (N_NODES + 1);
        const unsigned short* cl1 = col + E_EDGES;
        const unsigned short* cl2 = col + 2 * (size_t)E_EDGES;
        int e1 = rp1[r], E1 = rp1[r + 1];
        int e2 = rp2[r], E2 = rp2[r + 1];
        float a1x = 0.f, a1y = 0.f, a2x = 0.f, a2y = 0.f;
        while (e1 + 4 <= E1 && e2 + 4 <= E2) {
            int a0 = cl1[e1], a1 = cl1[e1+1], a2 = cl1[e1+2], a3 = cl1[e1+3];
            int b0 = cl2[e2], b1 = cl2[e2+1], b2 = cl2[e2+2], b3 = cl2[e2+3];
            float2 v0 = LDT(T1, a0), v1 = LDT(T1, a1), v2 = LDT(T1, a2), v3 = LDT(T1, a3);
            float2 u0 = LDT(T2, b0), u1 = LDT(T2, b1), u2 = LDT(T2, b2), u3 = LDT(T2, b3);
            a1x += (v0.x + v1.x) + (v2.x + v3.x); a1y += (v0.y + v1.y) + (v2.y + v3.y);
            a2x += (u0.x + u1.x) + (u2.x + u3.x); a2y += (u0.y + u1.y) + (u2.y + u3.y);
            e1 += 4; e2 += 4;
        }
        while (e1 + 4 <= E1) {
            int a0 = cl1[e1], a1 = cl1[e1+1], a2 = cl1[e1+2], a3 = cl1[e1+3];
            float2 v0 = LDT(T1, a0), v1 = LDT(T1, a1), v2 = LDT(T1, a2), v3 = LDT(T1, a3);
            a1x += (v0.x + v1.x) + (v2.x + v3.x); a1y += (v0.y + v1.y) + (v2.y + v3.y);
            e1 += 4;
        }
        while (e2 + 4 <= E2) {
            int b0 = cl2[e2], b1 = cl2[e2+1], b2 = cl2[e2+2], b3 = cl2[e2+3];
            float2 u0 = LDT(T2, b0), u1 = LDT(T2, b1), u2 = LDT(T2, b2), u3 = LDT(T2, b3);
            a2x += (u0.x + u1.x) + (u2.x + u3.x); a2y += (u0.y + u1.y) + (u2.y + u3.y);
            e2 += 4;
        }
        while (e1 < E1 && e2 < E2) {
            float2 v = LDT(T1, cl1[e1]), u = LDT(T2, cl2[e2]);
            a1x += v.x; a1y += v.y; a2x += u.x; a2y += u.y;
            e1++; e2++;
        }
        for (; e1 < E1; e1++) { float2 v = LDT(T1, cl1[e1]); a1x += v.x; a1y += v.y; }
        for (; e2 < E2; e2++) { float2 v = LDT(T2, cl2[e2]); a2x += v.x; a2y += v.y; }
        float s1 = scales[3 * N_NODES + r], s2 = scales[5 * N_NODES + r];
        float ox = a1x * s1 + a2x * s2 + b2rb[2 * l2] + b2f[2 * l2];
        float oy = a1y * s1 + a2y * s2 + b2rb[2 * l2 + 1] + b2f[2 * l2 + 1];
        *(__half2*)(oA + (size_t)r * 64 + 2 * l2) = __floats2half2_rn(ox, oy);
    }
#undef LDT
}

// ---------------- dispatch 9: scoring (pos + neg fused) ----------------------
__global__ __launch_bounds__(256) void score2(const __half* __restrict__ oA,
                                              const __half* __restrict__ oB,
                                              const int* __restrict__ ps,
                                              const int* __restrict__ pd,
                                              const int* __restrict__ ns,
                                              const int* __restrict__ nd,
                                              float* __restrict__ out) {
    int g = (blockIdx.x * blockDim.x + threadIdx.x) >> 4;
    int l = threadIdx.x & 15;
    int ng = (gridDim.x * blockDim.x) >> 4;
    const char* A = (const char*)oA;
    const char* B = (const char*)oB;
    unsigned loff = (unsigned)l << 3;
#define SCORE_LOOP(SRC, DST, OUT)                                               \
    for (int e0 = g * 2; e0 < E_EDGES; e0 += ng * 2) {                          \
        int e1 = e0 + 1;                                                        \
        int s0 = SRC[e0], d0 = DST[e0], s1 = SRC[e1], d1 = DST[e1];             \
        union { uint2 u; __half2 h[2]; } a0, b0, a1, b1;                        \
        a0.u = *(const uint2*)(A + (((unsigned)s0 << 7) + loff));               \
        b0.u = *(const uint2*)(B + (((unsigned)d0 << 7) + loff));               \
        a1.u = *(const uint2*)(A + (((unsigned)s1 << 7) + loff));               \
        b1.u = *(const uint2*)(B + (((unsigned)d1 << 7) + loff));               \
        float2 fa, fb;                                                          \
        fa = __half22float2(a0.h[0]); fb = __half22float2(b0.h[0]);             \
        float p0 = fa.x * fb.x + fa.y * fb.y;                                   \
        fa = __half22float2(a0.h[1]); fb = __half22float2(b0.h[1]);             \
        p0 += fa.x * fb.x + fa.y * fb.y;                                        \
        fa = __half22float2(a1.h[0]); fb = __half22float2(b1.h[0]);             \
        float p1 = fa.x * fb.x + fa.y * fb.y;                                   \
        fa = __half22float2(a1.h[1]); fb = __half22float2(b1.h[1]);             \
        p1 += fa.x * fb.x + fa.y * fb.y;                                        \
        p0 += __shfl_xor(p0, 8); p1 += __shfl_xor(p1, 8);                       \
        p0 += __shfl_xor(p0, 4); p1 += __shfl_xor(p1, 4);                       \
        p0 += __shfl_xor(p0, 2); p1 += __shfl_xor(p1, 2);                       \
        p0 += __shfl_xor(p0, 1); p1 += __shfl_xor(p1, 1);                       \
        if (l == 0) { OUT[e0] = p0; OUT[e1] = p1; }                             \
    }
    SCORE_LOOP(ps, pd, out)
    float* outn = out + E_EDGES;
    SCORE_LOOP(ns, nd, outn)
#undef SCORE_LOOP
}

// ---------------------------------------------------------------------------
extern "C" void kernel_launch(void* const* d_in, const int* in_sizes, int n_in,
                              void* d_out, int out_size, void* d_ws, size_t ws_size,
                              hipStream_t stream) {
    const float* feat_A     = (const float*)d_in[0];
    const float* feat_B     = (const float*)d_in[1];
    const int* rates_src    = (const int*)d_in[2];
    const int* rates_dst    = (const int*)d_in[3];
    const int* ratedby_src  = (const int*)d_in[4];
    const int* ratedby_dst  = (const int*)d_in[5];
    const int* follows_src  = (const int*)d_in[6];
    const int* follows_dst  = (const int*)d_in[7];
    const int* neg_src      = (const int*)d_in[8];
    const int* neg_dst      = (const int*)d_in[9];
    const float* W1_rates   = (const float*)d_in[10];
    const float* b1_rates   = (const float*)d_in[11];
    const float* W1_ratedby = (const float*)d_in[12];
    const float* b1_ratedby = (const float*)d_in[13];
    const float* W1_follows = (const float*)d_in[14];
    const float* b1_follows = (const float*)d_in[15];
    const float* W2_rates   = (const float*)d_in[16];
    const float* b2_rates   = (const float*)d_in[17];
    const float* W2_ratedby = (const float*)d_in[18];
    const float* b2_ratedby = (const float*)d_in[19];
    const float* W2_follows = (const float*)d_in[20];
    const float* b2_follows = (const float*)d_in[21];

    const int N = N_NODES, E = E_EDGES;

    char* ws = (char*)d_ws;
    size_t off = 0;
    auto alloc = [&](size_t bytes) -> void* {
        void* p = ws + off;
        off += (bytes + 255) & ~(size_t)255;
        return p;
    };
    float* scales = (float*)alloc((size_t)6 * N * 4);
    int* row_ptr  = (int*)alloc((size_t)3 * (N + 1) * 4);
    int* bphist   = (int*)alloc((size_t)6 * HB * NBUCK * 4);
    int* gbase    = (int*)alloc((size_t)6 * (NBUCK + 1) * 4);
    int* gcur     = (int*)alloc((size_t)6 * NBUCK * 4);
    unsigned short* col = (unsigned short*)alloc((size_t)3 * E * 2);
    unsigned* pairs = (unsigned*)alloc((size_t)3 * E * 4);
    unsigned char* sbytes = (unsigned char*)alloc((size_t)3 * E);
    __half* T012  = (__half*)alloc((size_t)3 * N * 128 * 2);
    __half* Tp    = (__half*)alloc((size_t)3 * N * 64 * 2);
    __half* hA    = (__half*)alloc((size_t)N * 128 * 2);
    __half* hB    = (__half*)alloc((size_t)N * 128 * 2);
    __half* oA    = (__half*)alloc((size_t)N * 64 * 2);
    __half* oB    = (__half*)alloc((size_t)N * 64 * 2);
    __half* Wt    = (__half*)alloc((size_t)73728 * 2);
    (void)ws_size;

    fused0<<<6 * HB + 96, 256, 0, stream>>>(W1_rates, W1_ratedby, W1_follows,
                                            W2_rates, W2_ratedby, W2_follows, Wt,
                                            rates_src, rates_dst, ratedby_src,
                                            ratedby_dst, follows_src, follows_dst,
                                            bphist);
    bucket_scan_par<<<6, 256, 0, stream>>>(bphist, gbase, gcur);
    fused_bin<<<dim3(256, 6), 256, 0, stream>>>(rates_src, rates_dst, ratedby_src,
                                                ratedby_dst, follows_src, follows_dst,
                                                gcur, pairs, sbytes);
    fused_finish<<<dim3(NBUCK, 6), 256, 0, stream>>>(pairs, sbytes, gbase,
                                                     row_ptr, scales, col);

    gemm_l1<<<3 * GB1, 256, 0, stream>>>(feat_A, feat_B, scales, Wt, T012);
    spmm_l1<<<(3 * N / 2) / 4, 256, 0, stream>>>(row_ptr, col, T012, scales,
                                                 b1_rates, b1_ratedby, b1_follows,
                                                 hB, hA);
    gemm_l2<<<3 * GB2, 256, 0, stream>>>(hA, hB, scales, Wt, Tp);
    spmm_l2<<<(3 * N / 2) / 8, 256, 0, stream>>>(row_ptr, col, Tp, scales,
                                                 b2_rates, b2_ratedby, b2_follows,
                                                 oB, oA);
    score2<<<8192, 256, 0, stream>>>(oA, oB, rates_src, rates_dst,
                                     neg_src, neg_dst, (float*)d_out);
}